// Round 2
// baseline (804.367 us; speedup 1.0000x reference)
//
#include <hip/hip_runtime.h>

#define NPIX (4*128*128)          // 65536
#define OUT_ELEMS (NPIX*64)       // 4194304

__device__ __forceinline__ int div25(int v) { return (v * 5243) >> 17; }   // exact 0..2600
__device__ __forceinline__ int div5(int v)  { return (v * 205) >> 10; }    // exact 0..1000
__device__ __forceinline__ int div6(int v)  { return (v * 43) >> 8; }      // exact 0..255

// ---------------------------------------------------------------------------
// K1: 1x1 convs q/k/v (+ copy x into out as fold-init). One wave per pixel.
// ---------------------------------------------------------------------------
__global__ __launch_bounds__(256) void k1_qkv(
    const float* __restrict__ x,
    const float* __restrict__ Wq, const float* __restrict__ bq,
    const float* __restrict__ Wk, const float* __restrict__ bk,
    const float* __restrict__ Wv, const float* __restrict__ bv,
    float* __restrict__ qws, float* __restrict__ kws, float* __restrict__ vws,
    float* __restrict__ out)
{
    __shared__ float sWv[64 * 65];
    __shared__ float sWqk[16 * 65];
    __shared__ float sx[4][64];

    int t = threadIdx.x;
    for (int e = t; e < 64 * 64; e += 256) {
        int o = e >> 6, c = e & 63;
        sWv[o * 65 + c] = Wv[e];
    }
    for (int e = t; e < 8 * 64; e += 256) {
        int o = e >> 6, c = e & 63;
        sWqk[o * 65 + c]       = Wq[e];
        sWqk[(o + 8) * 65 + c] = Wk[e];
    }

    int wid = t >> 6, lane = t & 63;
    int pix = blockIdx.x * 4 + wid;
    const float* xp = x + (size_t)pix * 64;
    float xv = xp[lane];
    sx[wid][lane] = xv;
    __syncthreads();

    const float* xb = sx[wid];
    bool isq = lane < 8;
    bool isk = (lane >= 8) && (lane < 16);
    float accv = bv[lane];
    float accq = isq ? bq[lane] : (isk ? bk[lane - 8] : 0.f);
    const float* wr  = sWv + lane * 65;
    const float* wr2 = sWqk + (lane & 7) * 65 + (isk ? 8 * 65 : 0);

    #pragma unroll
    for (int c = 0; c < 64; ++c) {
        float xc = xb[c];
        accv = fmaf(xc, wr[c], accv);
        accq = fmaf(xc, wr2[c], accq);
    }

    vws[(size_t)pix * 64 + lane] = accv;
    out[(size_t)pix * 64 + lane] = xv;
    if (isq)      qws[(size_t)pix * 8 + lane] = accq;
    else if (isk) kws[(size_t)pix * 8 + (lane - 8)] = accq;
}

// ---------------------------------------------------------------------------
// K2: 2x2 pixel tile per block (4 waves, 1 wave = 1 pixel).
// Shared 6x6 footprint staging + LDS fold aggregation -> 36 global atomics.
// ---------------------------------------------------------------------------
// LDS layout (floats):
//   [0    .. 2412)  SV [36][65]   (aliased later as FT [36][67], 2412 floats)
//   [2412 .. 2736)  SQ [36][9]
//   [2736 .. 3060)  SK [36][9]
//   [3060 .. 3860)  Qs [4][200]
//   [3860 .. 4660)  Ks [4][200]
//   [4660 .. 7476)  E  [4][704]   (rows [25][28])
//   [7476 .. 7604)  R  [4][32]
__global__ __launch_bounds__(256) void k2_attn(
    const float* __restrict__ qws, const float* __restrict__ kws,
    const float* __restrict__ vws, const float* __restrict__ gamma,
    float* __restrict__ out, float* __restrict__ attn)
{
    __shared__ float smem[7604];
    float* SV = smem;           // [36][65]
    float* FT = smem;           // [36][67] (aliased; SV dead by then)
    float* SQ = smem + 2412;    // [36][9]
    float* SK = smem + 2736;    // [36][9]
    float* QS = smem + 3060;    // [4][200]
    float* KS = smem + 3860;    // [4][200]
    float* EE = smem + 4660;    // [4][704]
    float* RR = smem + 7476;    // [4][32]

    int tid = threadIdx.x, wid = tid >> 6, lane = tid & 63;
    int bx = blockIdx.x;
    int img = bx >> 12;          // 4096 tiles per image
    int tt  = bx & 4095;
    int ty = (tt >> 6) << 1;
    int tx = (tt & 63) << 1;
    int a = wid >> 1, b = wid & 1;
    int y = ty + a, x = tx + b;
    size_t ibase = (size_t)img << 14;

    const float* vb = vws + ibase * 64;
    const float* qb = qws + ibase * 8;
    const float* kb = kws + ibase * 8;

    // ---- phase 1: cooperative staging of 6x6 footprint
    #pragma unroll
    for (int k = 0; k < 9; ++k) {
        int s = wid * 9 + k;
        int sy = div6(s), sx = s - sy * 6;
        int gy = ty + sy - 2, gx = tx + sx - 2;
        float val = 0.f;
        if ((unsigned)gy < 128u && (unsigned)gx < 128u)
            val = vb[(size_t)(((gy << 7) + gx) * 64 + lane)];
        SV[s * 65 + lane] = val;
    }
    #pragma unroll
    for (int i = 0; i < 2; ++i) {
        int e = tid + (i << 8);
        if (e < 288) {
            int s = e >> 3, cq = e & 7;
            int sy = div6(s), sx = s - sy * 6;
            int gy = ty + sy - 2, gx = tx + sx - 2;
            float qv = 0.f, kv = 0.f;
            if ((unsigned)gy < 128u && (unsigned)gx < 128u) {
                int off = ((gy << 7) + gx) * 8 + cq;
                qv = qb[off];
                kv = kb[off];
            }
            SQ[s * 9 + cq] = qv;
            SK[s * 9 + cq] = kv;
        }
    }
    __syncthreads();

    // ---- phase 3: per-wave flat Q/K views + V fragment registers
    float* Qw = QS + wid * 200;
    float* Kw = KS + wid * 200;
    #pragma unroll
    for (int i = 0; i < 4; ++i) {
        int e = lane + (i << 6);
        if (e < 200) {
            int cq = div25(e), p = e - cq * 25;
            int i5 = div5(p);
            int s = (a + i5) * 6 + (b + p - i5 * 5);
            Qw[e] = SQ[s * 9 + cq];
            Kw[e] = SK[s * 9 + cq];
        }
    }
    float vr[25];
    #pragma unroll
    for (int m = 0; m < 25; ++m) {
        int g = (m << 6) + lane;
        int cv = div25(g), p = g - cv * 25;
        int i5 = div5(p);
        int s = (a + i5) * 6 + (b + p - i5 * 5);
        vr[m] = SV[s * 65 + cv];
    }
    __syncthreads();   // SV dead after this point -> FT may be zeroed

    // ---- phase 5: zero fold tile; logits
    for (int e = tid; e < 2412; e += 256) FT[e] = 0.f;

    float* Ew = EE + wid * 704;
    #pragma unroll
    for (int i = 0; i < 10; ++i) {
        int e = lane + (i << 6);
        if (e < 625) {
            int n = div25(e), m = e - n * 25;
            const float4* qr = (const float4*)(Qw + (n << 3));
            const float4* kr = (const float4*)(Kw + (m << 3));
            float4 q0 = qr[0], q1 = qr[1], k0 = kr[0], k1 = kr[1];
            Ew[n * 28 + m] = q0.x * k0.x + q0.y * k0.y + q0.z * k0.z + q0.w * k0.w
                           + q1.x * k1.x + q1.y * k1.y + q1.z * k1.z + q1.w * k1.w;
        }
    }
    __syncthreads();

    // ---- phase 7: softmax rows (lanes 0..24)
    float* Rw = RR + wid * 32;
    if (lane < 25) {
        float* row = Ew + lane * 28;
        float mx = -3.4e38f;
        #pragma unroll
        for (int m = 0; m < 25; ++m) mx = fmaxf(mx, row[m]);
        float s = 0.f;
        #pragma unroll
        for (int m = 0; m < 25; ++m) {
            float ev = __expf(row[m] - mx);
            row[m] = ev;
            s += ev;
        }
        Rw[lane] = 1.f / s;
    }
    __syncthreads();

    // ---- phase 9: attn write, PV, LDS fold scatter
    size_t pixl = ibase + (size_t)((y << 7) + x);
    float* ab = attn + pixl * 625;
    #pragma unroll
    for (int i = 0; i < 10; ++i) {
        int e = lane + (i << 6);
        if (e < 625) {
            int n = div25(e), m = e - n * 25;
            ab[e] = Ew[n * 28 + m] * Rw[n];
        }
    }

    float g0 = gamma[0];
    float acc[25];
    #pragma unroll
    for (int n = 0; n < 25; ++n) {
        const float4* er = (const float4*)(Ew + n * 28);
        float aa = Ew[n * 28 + 24] * vr[24];
        #pragma unroll
        for (int q4 = 0; q4 < 6; ++q4) {
            float4 ev = er[q4];
            aa = fmaf(ev.x, vr[q4 * 4 + 0], aa);
            aa = fmaf(ev.y, vr[q4 * 4 + 1], aa);
            aa = fmaf(ev.z, vr[q4 * 4 + 2], aa);
            aa = fmaf(ev.w, vr[q4 * 4 + 3], aa);
        }
        acc[n] = aa * (Rw[n] * g0);
    }

    #pragma unroll
    for (int n = 0; n < 25; ++n) {
        int f = (n << 6) + lane;
        int c2 = div25(f), p = f - c2 * 25;
        int i5 = div5(p);
        int s = (a + i5) * 6 + (b + p - i5 * 5);
        atomicAdd(&smem[s * 67 + c2], acc[n]);   // ds_add_f32 into FT
    }
    __syncthreads();

    // ---- phase 11: 36 global atomic scatters per block
    float* ob = out + ibase * 64;
    #pragma unroll
    for (int k = 0; k < 9; ++k) {
        int s = wid * 9 + k;
        int sy = div6(s), sx = s - sy * 6;
        int oy = ty + sy - 2, ox = tx + sx - 2;
        if ((unsigned)oy < 128u && (unsigned)ox < 128u)
            atomicAdd(ob + (size_t)(((oy << 7) + ox) * 64 + lane), FT[s * 67 + lane]);
    }
}

// ---------------------------------------------------------------------------
extern "C" void kernel_launch(void* const* d_in, const int* in_sizes, int n_in,
                              void* d_out, int out_size, void* d_ws, size_t ws_size,
                              hipStream_t stream)
{
    const float* x  = (const float*)d_in[0];
    const float* Wq = (const float*)d_in[1];
    const float* bq = (const float*)d_in[2];
    const float* Wk = (const float*)d_in[3];
    const float* bk = (const float*)d_in[4];
    const float* Wv = (const float*)d_in[5];
    const float* bv = (const float*)d_in[6];
    const float* gm = (const float*)d_in[7];

    float* out  = (float*)d_out;               // [4,128,128,64]
    float* attn = out + OUT_ELEMS;             // [4,128,128,25,25]

    float* qws = (float*)d_ws;                 // [NPIX][8]
    float* kws = qws + (size_t)NPIX * 8;       // [NPIX][8]
    float* vws = kws + (size_t)NPIX * 8;       // [NPIX][64]

    hipLaunchKernelGGL(k1_qkv, dim3(NPIX / 4), dim3(256), 0, stream,
                       x, Wq, bq, Wk, bk, Wv, bv, qws, kws, vws, out);
    hipLaunchKernelGGL(k2_attn, dim3(NPIX / 4), dim3(256), 0, stream,
                       qws, kws, vws, gm, out, attn);
}

// Round 3
// 460.443 us; speedup vs baseline: 1.7469x; 1.7469x over previous
//
#include <hip/hip_runtime.h>
#include <hip/hip_fp16.h>

#define NPIX (4*128*128)          // 65536
#define OUT_ELEMS (NPIX*64)       // 4194304

__device__ __forceinline__ int div25(int v) { return (v * 5243) >> 17; }   // exact 0..2600
__device__ __forceinline__ int div5(int v)  { return (v * 205) >> 10; }    // exact 0..1000

// ---------------------------------------------------------------------------
// K1: 1x1 convs q/k/v. One wave per pixel. (out_init: fallback path only)
// ---------------------------------------------------------------------------
__global__ __launch_bounds__(256) void k1_qkv(
    const float* __restrict__ x,
    const float* __restrict__ Wq, const float* __restrict__ bq,
    const float* __restrict__ Wk, const float* __restrict__ bk,
    const float* __restrict__ Wv, const float* __restrict__ bv,
    float* __restrict__ qws, float* __restrict__ kws, float* __restrict__ vws,
    float* __restrict__ out_init)
{
    __shared__ float sWv[64 * 65];
    __shared__ float sWqk[16 * 65];
    __shared__ float sx[4][64];

    int t = threadIdx.x;
    for (int e = t; e < 64 * 64; e += 256) {
        int o = e >> 6, c = e & 63;
        sWv[o * 65 + c] = Wv[e];
    }
    for (int e = t; e < 8 * 64; e += 256) {
        int o = e >> 6, c = e & 63;
        sWqk[o * 65 + c]       = Wq[e];
        sWqk[(o + 8) * 65 + c] = Wk[e];
    }

    int wid = t >> 6, lane = t & 63;
    int pix = blockIdx.x * 4 + wid;
    float xv = x[(size_t)pix * 64 + lane];
    sx[wid][lane] = xv;
    __syncthreads();   // real cross-wave share (weights)

    const float* xb = sx[wid];
    bool isq = lane < 8;
    bool isk = (lane >= 8) && (lane < 16);
    float accv = bv[lane];
    float accq = isq ? bq[lane] : (isk ? bk[lane - 8] : 0.f);
    const float* wr  = sWv + lane * 65;
    const float* wr2 = sWqk + (lane & 7) * 65 + (isk ? 8 * 65 : 0);

    #pragma unroll
    for (int c = 0; c < 64; ++c) {
        float xc = xb[c];
        accv = fmaf(xc, wr[c], accv);
        accq = fmaf(xc, wr2[c], accq);
    }

    vws[(size_t)pix * 64 + lane] = accv;
    if (out_init) out_init[(size_t)pix * 64 + lane] = xv;
    if (isq)      qws[(size_t)pix * 8 + lane] = accq;
    else if (isk) kws[(size_t)pix * 8 + (lane - 8)] = accq;
}

// ---------------------------------------------------------------------------
// Shared per-wave attention body (no barriers: all LDS regions are per-wave).
// Computes exp-rows in E, 1/sum in R, V fragments in vr, writes attn.
// ---------------------------------------------------------------------------
__device__ __forceinline__ void attn_core(
    int lane, int y, int x, size_t ibase,
    const float* __restrict__ qws, const float* __restrict__ kws,
    const float* __restrict__ vws, float* __restrict__ attn,
    float* V, float* Qs, float* Ks, float* E, float* R, float vr[25])
{
    const float* vb = vws + ibase * 64;
    #pragma unroll
    for (int p = 0; p < 25; ++p) {
        int i5 = div5(p);
        int yy = y + i5 - 2, xx = x + (p - i5 * 5) - 2;
        float val = 0.f;
        if ((unsigned)yy < 128u && (unsigned)xx < 128u)
            val = vb[(size_t)(((yy << 7) + xx) * 64 + lane)];
        V[p * 65 + lane] = val;
    }
    const float* qb = qws + ibase * 8;
    const float* kb = kws + ibase * 8;
    #pragma unroll
    for (int i = 0; i < 4; ++i) {
        int e = lane + (i << 6);
        if (e < 200) {
            int cq = div25(e), p = e - cq * 25;
            int i5 = div5(p);
            int yy = y + i5 - 2, xx = x + (p - i5 * 5) - 2;
            float qv = 0.f, kv = 0.f;
            if ((unsigned)yy < 128u && (unsigned)xx < 128u) {
                int off = ((yy << 7) + xx) * 8 + cq;
                qv = qb[off];
                kv = kb[off];
            }
            Qs[e] = qv;
            Ks[e] = kv;
        }
    }

    #pragma unroll
    for (int m = 0; m < 25; ++m) {
        int g = (m << 6) + lane;
        int cv = div25(g), p = g - cv * 25;
        vr[m] = V[p * 65 + cv];
    }

    #pragma unroll
    for (int i = 0; i < 10; ++i) {
        int e = lane + (i << 6);
        if (e < 625) {
            int n = div25(e), m = e - n * 25;
            const float4* qr = (const float4*)(Qs + (n << 3));
            const float4* kr = (const float4*)(Ks + (m << 3));
            float4 q0 = qr[0], q1 = qr[1], k0 = kr[0], k1 = kr[1];
            E[n * 28 + m] = q0.x * k0.x + q0.y * k0.y + q0.z * k0.z + q0.w * k0.w
                          + q1.x * k1.x + q1.y * k1.y + q1.z * k1.z + q1.w * k1.w;
        }
    }

    if (lane < 25) {
        float* row = E + lane * 28;
        float mx = -3.4e38f;
        #pragma unroll
        for (int m = 0; m < 25; ++m) mx = fmaxf(mx, row[m]);
        float s = 0.f;
        #pragma unroll
        for (int m = 0; m < 25; ++m) {
            float ev = __expf(row[m] - mx);
            row[m] = ev;
            s += ev;
        }
        R[lane] = 1.f / s;
    }

    size_t pixl = ibase + (size_t)((y << 7) + x);
    float* ab = attn + pixl * 625;
    #pragma unroll
    for (int i = 0; i < 10; ++i) {
        int e = lane + (i << 6);
        if (e < 625) {
            int n = div25(e), m = e - n * 25;
            ab[e] = E[n * 28 + m] * R[n];
        }
    }
}

__device__ __forceinline__ void pv_core(const float* E, const float* R,
                                        const float vr[25], float scale, float acc[25])
{
    #pragma unroll
    for (int n = 0; n < 25; ++n) {
        const float4* er = (const float4*)(E + n * 28);
        float aa = E[n * 28 + 24] * vr[24];
        #pragma unroll
        for (int q4 = 0; q4 < 6; ++q4) {
            float4 ev = er[q4];
            aa = fmaf(ev.x, vr[q4 * 4 + 0], aa);
            aa = fmaf(ev.y, vr[q4 * 4 + 1], aa);
            aa = fmaf(ev.z, vr[q4 * 4 + 2], aa);
            aa = fmaf(ev.w, vr[q4 * 4 + 3], aa);
        }
        acc[n] = aa * (R[n] * scale);
    }
}

// ---------------------------------------------------------------------------
// K2 main: per-pixel attention, barrier-free; local -> fp16 ws in [pix][p][c]
// ---------------------------------------------------------------------------
__global__ __launch_bounds__(256) void k2_attn_ws(
    const float* __restrict__ qws, const float* __restrict__ kws,
    const float* __restrict__ vws,
    float* __restrict__ attn, __half* __restrict__ lws)
{
    __shared__ float sV[4][1632];
    __shared__ float sQ[4][200];
    __shared__ float sK[4][200];
    __shared__ float sE[4][704];
    __shared__ float sR[4][32];

    int tid = threadIdx.x, wid = tid >> 6, lane = tid & 63;
    int pix = blockIdx.x * 4 + wid;
    int b = pix >> 14, y = (pix >> 7) & 127, x = pix & 127;
    size_t ibase = (size_t)b << 14;

    float vr[25];
    attn_core(lane, y, x, ibase, qws, kws, vws, attn,
              sV[wid], sQ[wid], sK[wid], sE[wid], sR[wid], vr);

    float acc[25];
    pv_core(sE[wid], sR[wid], vr, 1.0f, acc);   // gamma applied in K3

    // remap local[n][c] -> fold layout [p][c] via per-wave LDS (alias V)
    float* LB = sV[wid];
    #pragma unroll
    for (int n = 0; n < 25; ++n) LB[(n << 6) + lane] = acc[n];

    __half* lp = lws + (ibase + (size_t)((y << 7) + x)) * 1600;
    #pragma unroll
    for (int p = 0; p < 25; ++p)
        lp[(p << 6) + lane] = __float2half(LB[lane * 25 + p]);
}

// ---------------------------------------------------------------------------
// K3: non-atomic gather fold. out = x + gamma * sum of 25 neighbor slices.
// ---------------------------------------------------------------------------
__global__ __launch_bounds__(256) void k3_fold(
    const float* __restrict__ x, const __half* __restrict__ lws,
    const float* __restrict__ gamma, float* __restrict__ out)
{
    int tid = threadIdx.x, wid = tid >> 6, lane = tid & 63;
    int pix = blockIdx.x * 4 + wid;
    int b = pix >> 14, y = (pix >> 7) & 127, xx = pix & 127;
    const __half* lb = lws + ((size_t)b << 14) * 1600;

    float s = 0.f;
    #pragma unroll
    for (int i = 0; i < 5; ++i) {
        int cy = y + 2 - i;
        if ((unsigned)cy >= 128u) continue;
        #pragma unroll
        for (int j = 0; j < 5; ++j) {
            int cx = xx + 2 - j;
            if ((unsigned)cx >= 128u) continue;
            s += __half2float(lb[(size_t)((cy << 7) + cx) * 1600 + ((i * 5 + j) << 6) + lane]);
        }
    }
    size_t o = (size_t)pix * 64 + lane;
    out[o] = fmaf(gamma[0], s, x[o]);
}

// ---------------------------------------------------------------------------
// K2 fallback (small ws): per-pixel attention + direct global atomic fold.
// ---------------------------------------------------------------------------
__global__ __launch_bounds__(256) void k2_attn_atomic(
    const float* __restrict__ qws, const float* __restrict__ kws,
    const float* __restrict__ vws, const float* __restrict__ gamma,
    float* __restrict__ out, float* __restrict__ attn)
{
    __shared__ float sV[4][1632];
    __shared__ float sQ[4][200];
    __shared__ float sK[4][200];
    __shared__ float sE[4][704];
    __shared__ float sR[4][32];

    int tid = threadIdx.x, wid = tid >> 6, lane = tid & 63;
    int pix = blockIdx.x * 4 + wid;
    int b = pix >> 14, y = (pix >> 7) & 127, x = pix & 127;
    size_t ibase = (size_t)b << 14;

    float vr[25];
    attn_core(lane, y, x, ibase, qws, kws, vws, attn,
              sV[wid], sQ[wid], sK[wid], sE[wid], sR[wid], vr);

    float acc[25];
    pv_core(sE[wid], sR[wid], vr, gamma[0], acc);

    float* LB = sV[wid];
    #pragma unroll
    for (int n = 0; n < 25; ++n) LB[(n << 6) + lane] = acc[n];

    float* ob = out + ibase * 64;
    #pragma unroll
    for (int p = 0; p < 25; ++p) {
        int i5 = div5(p);
        int ty = y + i5 - 2, tx = x + (p - i5 * 5) - 2;
        if ((unsigned)ty < 128u && (unsigned)tx < 128u)
            atomicAdd(ob + (size_t)(((ty << 7) + tx) * 64 + lane), LB[lane * 25 + p]);
    }
}

// ---------------------------------------------------------------------------
extern "C" void kernel_launch(void* const* d_in, const int* in_sizes, int n_in,
                              void* d_out, int out_size, void* d_ws, size_t ws_size,
                              hipStream_t stream)
{
    const float* x  = (const float*)d_in[0];
    const float* Wq = (const float*)d_in[1];
    const float* bq = (const float*)d_in[2];
    const float* Wk = (const float*)d_in[3];
    const float* bk = (const float*)d_in[4];
    const float* Wv = (const float*)d_in[5];
    const float* bv = (const float*)d_in[6];
    const float* gm = (const float*)d_in[7];

    float* out  = (float*)d_out;               // [4,128,128,64]
    float* attn = out + OUT_ELEMS;             // [4,128,128,25,25]

    float* qws = (float*)d_ws;                 // [NPIX][8]
    float* kws = qws + (size_t)NPIX * 8;       // [NPIX][8]
    float* vws = kws + (size_t)NPIX * 8;       // [NPIX][64]
    __half* lws = (__half*)(vws + (size_t)NPIX * 64);   // [NPIX][25][64] fp16

    const size_t need = (size_t)NPIX * 80 * 4 + (size_t)NPIX * 1600 * 2; // 230.7 MB

    if (ws_size >= need) {
        hipLaunchKernelGGL(k1_qkv, dim3(NPIX / 4), dim3(256), 0, stream,
                           x, Wq, bq, Wk, bk, Wv, bv, qws, kws, vws, (float*)nullptr);
        hipLaunchKernelGGL(k2_attn_ws, dim3(NPIX / 4), dim3(256), 0, stream,
                           qws, kws, vws, attn, lws);
        hipLaunchKernelGGL(k3_fold, dim3(NPIX / 4), dim3(256), 0, stream,
                           x, lws, gm, out);
    } else {
        hipLaunchKernelGGL(k1_qkv, dim3(NPIX / 4), dim3(256), 0, stream,
                           x, Wq, bq, Wk, bk, Wv, bv, qws, kws, vws, out);
        hipLaunchKernelGGL(k2_attn_atomic, dim3(NPIX / 4), dim3(256), 0, stream,
                           qws, kws, vws, gm, out, attn);
    }
}

// Round 6
// 420.102 us; speedup vs baseline: 1.9147x; 1.0960x over previous
//
#include <hip/hip_runtime.h>
#include <hip/hip_fp16.h>

#define NPIX (4*128*128)          // 65536
#define OUT_ELEMS (NPIX*64)       // 4194304

typedef _Float16 half8 __attribute__((ext_vector_type(8)));
typedef float f32x16 __attribute__((ext_vector_type(16)));

__device__ __forceinline__ int div25(int v) { return (v * 5243) >> 17; }   // exact 0..2600
__device__ __forceinline__ int div5(int v)  { return (v * 205) >> 10; }    // exact 0..1000

// ---------------------------------------------------------------------------
// K1: 1x1 convs q/k/v. 2048 blocks; each wave handles 8 pixels; weights
// staged in LDS once per block (amortized 32 pixels).
// ---------------------------------------------------------------------------
__global__ __launch_bounds__(256) void k1_qkv(
    const float* __restrict__ x,
    const float* __restrict__ Wq, const float* __restrict__ bq,
    const float* __restrict__ Wk, const float* __restrict__ bk,
    const float* __restrict__ Wv, const float* __restrict__ bv,
    float* __restrict__ qws, float* __restrict__ kws, float* __restrict__ vws,
    float* __restrict__ out_init)
{
    __shared__ float sWv[64 * 65];
    __shared__ float sWqk[16 * 65];

    int t = threadIdx.x;
    for (int e = t; e < 64 * 64; e += 256) sWv[(e >> 6) * 65 + (e & 63)] = Wv[e];
    for (int e = t; e < 8 * 64; e += 256) {
        int o = e >> 6, c = e & 63;
        sWqk[o * 65 + c]       = Wq[e];
        sWqk[(o + 8) * 65 + c] = Wk[e];
    }
    __syncthreads();   // weights shared cross-wave (only barrier in k1)

    int wid = t >> 6, lane = t & 63;
    bool isq = lane < 8;
    bool isk = (lane >= 8) && (lane < 16);
    const float* wr  = sWv + lane * 65;
    const float* wr2 = sWqk + (lane & 7) * 65 + (isk ? 8 * 65 : 0);
    float bvl = bv[lane];
    float bql = isq ? bq[lane] : (isk ? bk[lane - 8] : 0.f);

    #pragma unroll 1
    for (int i = 0; i < 8; ++i) {
        int pix = blockIdx.x * 32 + wid * 8 + i;
        float xv = x[(size_t)pix * 64 + lane];
        float accv = bvl, accq = bql;
        #pragma unroll
        for (int cc = 0; cc < 64; ++cc) {
            float xc = __shfl(xv, cc);
            accv = fmaf(xc, wr[cc], accv);
            accq = fmaf(xc, wr2[cc], accq);
        }
        vws[(size_t)pix * 64 + lane] = accv;
        if (out_init) out_init[(size_t)pix * 64 + lane] = xv;
        if (isq)      qws[(size_t)pix * 8 + lane] = accq;
        else if (isk) kws[(size_t)pix * 8 + (lane - 8)] = accq;
    }
}

// ---------------------------------------------------------------------------
// K2 main: per-pixel attention (barrier-free). QK^T + softmax + attn in fp32;
// PV via 4x v_mfma_f32_32x32x16_f16 with the module's channel-major
// reinterpretation applied to BOTH operand sides:
//   B[k][cc] = flat1600[k*64+cc] = V[(g)%25][(g)/25], g = k*64+cc
// Per-wave LDS W[2976]:
//   V[0:1632]   (25x65 staged patch; later aliased as LB[0:1600])
//   Qs[1632:1832] Ks[1832:2032] E[2032:2936] (32 rows x 28 + 8) R[2936:2968]
// ---------------------------------------------------------------------------
__global__ __launch_bounds__(256) void k2_attn_ws(
    const float* __restrict__ qws, const float* __restrict__ kws,
    const float* __restrict__ vws,
    float* __restrict__ attn, __half* __restrict__ lws)
{
    __shared__ float smem[4 * 2976];

    int tid = threadIdx.x, wid = tid >> 6, lane = tid & 63;
    float* W  = smem + wid * 2976;
    float* V  = W;            // [25][65]
    float* LB = W;            // [1600] fold-remap buffer (aliases V)
    float* Qs = W + 1632;     // [200]
    float* Ks = W + 1832;     // [200]
    float* E  = W + 2032;     // [32][28] + 8 pad floats
    float* R  = W + 2936;     // [32]

    int pix = blockIdx.x * 4 + wid;
    int b = pix >> 14, y = (pix >> 7) & 127, x = pix & 127;
    size_t ibase = (size_t)b << 14;

    // zero E (incl. pad rows/cols -> A-side garbage is 0, never NaN)
    #pragma unroll
    for (int e = lane; e < 904; e += 64) E[e] = 0.f;

    // ---- stage V patch coalesced: V[p][cv] = v(cv, y+di-2, x+dj-2), 0-padded
    const float* vb = vws + ibase * 64;
    #pragma unroll
    for (int p = 0; p < 25; ++p) {
        int i5 = div5(p);
        int yy = y + i5 - 2, xx = x + (p - i5 * 5) - 2;
        float val = 0.f;
        if ((unsigned)yy < 128u && (unsigned)xx < 128u)
            val = vb[(size_t)(((yy << 7) + xx) * 64 + lane)];
        V[p * 65 + lane] = val;
    }

    // ---- stage Q,K flat: [cq*25+p]
    const float* qb = qws + ibase * 8;
    const float* kb = kws + ibase * 8;
    #pragma unroll
    for (int i = 0; i < 4; ++i) {
        int e = lane + (i << 6);
        if (e < 200) {
            int cq = div25(e), p = e - cq * 25;
            int i5 = div5(p);
            int yy = y + i5 - 2, xx = x + (p - i5 * 5) - 2;
            float qv = 0.f, kv = 0.f;
            if ((unsigned)yy < 128u && (unsigned)xx < 128u) {
                int off = ((yy << 7) + xx) * 8 + cq;
                qv = qb[off];
                kv = kb[off];
            }
            Qs[e] = qv;
            Ks[e] = kv;
        }
    }

    // ---- logits[n][m] fp32
    #pragma unroll
    for (int i = 0; i < 10; ++i) {
        int e = lane + (i << 6);
        if (e < 625) {
            int n = div25(e), m = e - n * 25;
            const float4* qr = (const float4*)(Qs + (n << 3));
            const float4* kr = (const float4*)(Ks + (m << 3));
            float4 q0 = qr[0], q1 = qr[1], k0 = kr[0], k1 = kr[1];
            E[n * 28 + m] = q0.x * k0.x + q0.y * k0.y + q0.z * k0.z + q0.w * k0.w
                          + q1.x * k1.x + q1.y * k1.y + q1.z * k1.z + q1.w * k1.w;
        }
    }

    // ---- softmax rows (lanes 0..24): E <- exp(row - max), R <- 1/sum
    if (lane < 25) {
        float* row = E + lane * 28;
        float mx = -3.4e38f;
        #pragma unroll
        for (int m = 0; m < 25; ++m) mx = fmaxf(mx, row[m]);
        float s = 0.f;
        #pragma unroll
        for (int m = 0; m < 25; ++m) {
            float ev = __expf(row[m] - mx);
            row[m] = ev;
            s += ev;
        }
        R[lane] = 1.f / s;
    }

    // ---- attn output (fp32, exact path)
    float* ab = attn + (ibase + (size_t)((y << 7) + x)) * 625;
    #pragma unroll
    for (int i = 0; i < 10; ++i) {
        int e = lane + (i << 6);
        if (e < 625) {
            int n = div25(e), m = e - n * 25;
            ab[e] = E[n * 28 + m] * R[n];
        }
    }

    // ---- PV via MFMA. A[n][k] = exp row n (f16); B[k][cc] = reinterpreted V.
    int h  = lane >> 5;      // half-wave
    int lo = lane & 31;

    half8 afr[2];
    #pragma unroll
    for (int s = 0; s < 2; ++s) {
        const float4* ep = (const float4*)(E + lo * 28 + 16 * s + 8 * h);
        float4 p0 = ep[0], p1 = ep[1];
        afr[s][0] = (_Float16)p0.x; afr[s][1] = (_Float16)p0.y;
        afr[s][2] = (_Float16)p0.z; afr[s][3] = (_Float16)p0.w;
        afr[s][4] = (_Float16)p1.x; afr[s][5] = (_Float16)p1.y;
        afr[s][6] = (_Float16)p1.z; afr[s][7] = (_Float16)p1.w;
    }

    f32x16 acc0 = {0,0,0,0,0,0,0,0,0,0,0,0,0,0,0,0};
    f32x16 acc1 = {0,0,0,0,0,0,0,0,0,0,0,0,0,0,0,0};
    #pragma unroll
    for (int s = 0; s < 2; ++s) {
        half8 b0, b1;
        #pragma unroll
        for (int j = 0; j < 8; ++j) {
            int k = 16 * s + 8 * h + j;            // logical k (patch-dim row)
            int g0 = (k << 6) + lo;                // flat idx, col = lo
            int g1 = g0 + 32;                      // flat idx, col = lo+32
            int cv0 = div25(g0), p0 = g0 - cv0 * 25;
            int cv1 = div25(g1), p1 = g1 - cv1 * 25;
            bool ok = (k < 25);                    // g<1600 <=> k<25
            b0[j] = ok ? (_Float16)V[p0 * 65 + cv0] : (_Float16)0.f;
            b1[j] = ok ? (_Float16)V[p1 * 65 + cv1] : (_Float16)0.f;
        }
        acc0 = __builtin_amdgcn_mfma_f32_32x32x16_f16(afr[s], b0, acc0, 0, 0, 0);
        acc1 = __builtin_amdgcn_mfma_f32_32x32x16_f16(afr[s], b1, acc1, 0, 0, 0);
    }

    // ---- fold-remap: LB[n*64 + cc] = local[n][cc] (normalized); LB aliases V
    #pragma unroll
    for (int r16 = 0; r16 < 16; ++r16) {
        int row = (r16 & 3) + 8 * (r16 >> 2) + 4 * h;   // D row = patch-dim n
        if (row < 25) {
            float rn = R[row];
            LB[(row << 6) + lo]      = acc0[r16] * rn;
            LB[(row << 6) + 32 + lo] = acc1[r16] * rn;
        }
    }

    // ---- store fp16 local in fold layout: lws[pix][p][c] = flat[c*25+p]
    __half* lp = lws + (ibase + (size_t)((y << 7) + x)) * 1600;
    #pragma unroll
    for (int p = 0; p < 25; ++p)
        lp[(p << 6) + lane] = __float2half(LB[lane * 25 + p]);
}

// ---------------------------------------------------------------------------
// K3: non-atomic gather fold. out = x + gamma * sum of 25 neighbor slices.
// ---------------------------------------------------------------------------
__global__ __launch_bounds__(256) void k3_fold(
    const float* __restrict__ x, const __half* __restrict__ lws,
    const float* __restrict__ gamma, float* __restrict__ out)
{
    int tid = threadIdx.x, wid = tid >> 6, lane = tid & 63;
    int pix = blockIdx.x * 4 + wid;
    int b = pix >> 14, y = (pix >> 7) & 127, xx = pix & 127;
    const __half* lb = lws + ((size_t)b << 14) * 1600;

    float s = 0.f;
    #pragma unroll
    for (int i = 0; i < 5; ++i) {
        int cy = y + 2 - i;
        if ((unsigned)cy >= 128u) continue;
        #pragma unroll
        for (int j = 0; j < 5; ++j) {
            int cx = xx + 2 - j;
            if ((unsigned)cx >= 128u) continue;
            s += __half2float(lb[(size_t)((cy << 7) + cx) * 1600 + ((i * 5 + j) << 6) + lane]);
        }
    }
    size_t o = (size_t)pix * 64 + lane;
    out[o] = fmaf(gamma[0], s, x[o]);
}

// ---------------------------------------------------------------------------
// Fallback path (small ws): R3's proven per-pixel attention + atomic fold.
// ---------------------------------------------------------------------------
__device__ __forceinline__ void attn_core_fb(
    int lane, int y, int x, size_t ibase,
    const float* __restrict__ qws, const float* __restrict__ kws,
    const float* __restrict__ vws, float* __restrict__ attn,
    float* V, float* Qs, float* Ks, float* E, float* R, float vr[25])
{
    const float* vb = vws + ibase * 64;
    #pragma unroll
    for (int p = 0; p < 25; ++p) {
        int i5 = div5(p);
        int yy = y + i5 - 2, xx = x + (p - i5 * 5) - 2;
        float val = 0.f;
        if ((unsigned)yy < 128u && (unsigned)xx < 128u)
            val = vb[(size_t)(((yy << 7) + xx) * 64 + lane)];
        V[p * 65 + lane] = val;
    }
    const float* qb = qws + ibase * 8;
    const float* kb = kws + ibase * 8;
    #pragma unroll
    for (int i = 0; i < 4; ++i) {
        int e = lane + (i << 6);
        if (e < 200) {
            int cq = div25(e), p = e - cq * 25;
            int i5 = div5(p);
            int yy = y + i5 - 2, xx = x + (p - i5 * 5) - 2;
            float qv = 0.f, kv = 0.f;
            if ((unsigned)yy < 128u && (unsigned)xx < 128u) {
                int off = ((yy << 7) + xx) * 8 + cq;
                qv = qb[off];
                kv = kb[off];
            }
            Qs[e] = qv;
            Ks[e] = kv;
        }
    }
    #pragma unroll
    for (int m = 0; m < 25; ++m) {
        int g = (m << 6) + lane;
        int cv = div25(g), p = g - cv * 25;
        vr[m] = V[p * 65 + cv];
    }
    #pragma unroll
    for (int i = 0; i < 10; ++i) {
        int e = lane + (i << 6);
        if (e < 625) {
            int n = div25(e), m = e - n * 25;
            const float4* qr = (const float4*)(Qs + (n << 3));
            const float4* kr = (const float4*)(Ks + (m << 3));
            float4 q0 = qr[0], q1 = qr[1], k0 = kr[0], k1 = kr[1];
            E[n * 28 + m] = q0.x * k0.x + q0.y * k0.y + q0.z * k0.z + q0.w * k0.w
                          + q1.x * k1.x + q1.y * k1.y + q1.z * k1.z + q1.w * k1.w;
        }
    }
    if (lane < 25) {
        float* row = E + lane * 28;
        float mx = -3.4e38f;
        #pragma unroll
        for (int m = 0; m < 25; ++m) mx = fmaxf(mx, row[m]);
        float s = 0.f;
        #pragma unroll
        for (int m = 0; m < 25; ++m) {
            float ev = __expf(row[m] - mx);
            row[m] = ev;
            s += ev;
        }
        R[lane] = 1.f / s;
    }
    float* ab = attn + (ibase + (size_t)((y << 7) + x)) * 625;
    #pragma unroll
    for (int i = 0; i < 10; ++i) {
        int e = lane + (i << 6);
        if (e < 625) {
            int n = div25(e), m = e - n * 25;
            ab[e] = E[n * 28 + m] * R[n];
        }
    }
}

__global__ __launch_bounds__(256) void k2_attn_atomic(
    const float* __restrict__ qws, const float* __restrict__ kws,
    const float* __restrict__ vws, const float* __restrict__ gamma,
    float* __restrict__ out, float* __restrict__ attn)
{
    __shared__ float sV[4][1632];
    __shared__ float sQ[4][200];
    __shared__ float sK[4][200];
    __shared__ float sE[4][704];
    __shared__ float sR[4][32];

    int tid = threadIdx.x, wid = tid >> 6, lane = tid & 63;
    int pix = blockIdx.x * 4 + wid;
    int b = pix >> 14, y = (pix >> 7) & 127, x = pix & 127;
    size_t ibase = (size_t)b << 14;

    float vr[25];
    attn_core_fb(lane, y, x, ibase, qws, kws, vws, attn,
                 sV[wid], sQ[wid], sK[wid], sE[wid], sR[wid], vr);

    float g0 = gamma[0];
    float acc[25];
    float* E = sE[wid];
    float* R = sR[wid];
    #pragma unroll
    for (int n = 0; n < 25; ++n) {
        const float4* er = (const float4*)(E + n * 28);
        float aa = E[n * 28 + 24] * vr[24];
        #pragma unroll
        for (int q4 = 0; q4 < 6; ++q4) {
            float4 ev = er[q4];
            aa = fmaf(ev.x, vr[q4 * 4 + 0], aa);
            aa = fmaf(ev.y, vr[q4 * 4 + 1], aa);
            aa = fmaf(ev.z, vr[q4 * 4 + 2], aa);
            aa = fmaf(ev.w, vr[q4 * 4 + 3], aa);
        }
        acc[n] = aa * (R[n] * g0);
    }

    float* LB = sV[wid];
    #pragma unroll
    for (int n = 0; n < 25; ++n) LB[(n << 6) + lane] = acc[n];

    float* ob = out + ibase * 64;
    #pragma unroll
    for (int p = 0; p < 25; ++p) {
        int i5 = div5(p);
        int ty = y + i5 - 2, tx = x + (p - i5 * 5) - 2;
        if ((unsigned)ty < 128u && (unsigned)tx < 128u)
            atomicAdd(ob + (size_t)(((ty << 7) + tx) * 64 + lane), LB[lane * 25 + p]);
    }
}

// ---------------------------------------------------------------------------
extern "C" void kernel_launch(void* const* d_in, const int* in_sizes, int n_in,
                              void* d_out, int out_size, void* d_ws, size_t ws_size,
                              hipStream_t stream)
{
    const float* x  = (const float*)d_in[0];
    const float* Wq = (const float*)d_in[1];
    const float* bq = (const float*)d_in[2];
    const float* Wk = (const float*)d_in[3];
    const float* bk = (const float*)d_in[4];
    const float* Wv = (const float*)d_in[5];
    const float* bv = (const float*)d_in[6];
    const float* gm = (const float*)d_in[7];

    float* out  = (float*)d_out;               // [4,128,128,64]
    float* attn = out + OUT_ELEMS;             // [4,128,128,25,25]

    float* qws = (float*)d_ws;                 // [NPIX][8]
    float* kws = qws + (size_t)NPIX * 8;       // [NPIX][8]
    float* vws = kws + (size_t)NPIX * 8;       // [NPIX][64]
    __half* lws = (__half*)(vws + (size_t)NPIX * 64);   // [NPIX][25][64] fp16

    const size_t need = (size_t)NPIX * 80 * 4 + (size_t)NPIX * 1600 * 2; // 230.7 MB

    if (ws_size >= need) {
        hipLaunchKernelGGL(k1_qkv, dim3(NPIX / 32), dim3(256), 0, stream,
                           x, Wq, bq, Wk, bk, Wv, bv, qws, kws, vws, (float*)nullptr);
        hipLaunchKernelGGL(k2_attn_ws, dim3(NPIX / 4), dim3(256), 0, stream,
                           qws, kws, vws, attn, lws);
        hipLaunchKernelGGL(k3_fold, dim3(NPIX / 4), dim3(256), 0, stream,
                           x, lws, gm, out);
    } else {
        hipLaunchKernelGGL(k1_qkv, dim3(NPIX / 32), dim3(256), 0, stream,
                           x, Wq, bq, Wk, bk, Wv, bv, qws, kws, vws, out);
        hipLaunchKernelGGL(k2_attn_atomic, dim3(NPIX / 4), dim3(256), 0, stream,
                           qws, kws, vws, gm, out, attn);
    }
}

// Round 7
// 333.870 us; speedup vs baseline: 2.4092x; 1.2583x over previous
//
#include <hip/hip_runtime.h>
#include <hip/hip_fp16.h>

#define NPIX (4*128*128)          // 65536
#define OUT_ELEMS (NPIX*64)       // 4194304

typedef _Float16 half8 __attribute__((ext_vector_type(8)));
typedef float f32x16 __attribute__((ext_vector_type(16)));

__device__ __forceinline__ int div25(int v) { return (v * 5243) >> 17; }   // exact 0..2600
__device__ __forceinline__ int div5(int v)  { return (v * 205) >> 10; }    // exact 0..1000

// ---------------------------------------------------------------------------
// K1: 1x1 convs q/k/v. 2048 blocks; each wave handles 8 pixels.
// ---------------------------------------------------------------------------
__global__ __launch_bounds__(256) void k1_qkv(
    const float* __restrict__ x,
    const float* __restrict__ Wq, const float* __restrict__ bq,
    const float* __restrict__ Wk, const float* __restrict__ bk,
    const float* __restrict__ Wv, const float* __restrict__ bv,
    float* __restrict__ qws, float* __restrict__ kws, float* __restrict__ vws,
    float* __restrict__ out_init)
{
    __shared__ float sWv[64 * 65];
    __shared__ float sWqk[16 * 65];

    int t = threadIdx.x;
    for (int e = t; e < 64 * 64; e += 256) sWv[(e >> 6) * 65 + (e & 63)] = Wv[e];
    for (int e = t; e < 8 * 64; e += 256) {
        int o = e >> 6, c = e & 63;
        sWqk[o * 65 + c]       = Wq[e];
        sWqk[(o + 8) * 65 + c] = Wk[e];
    }
    __syncthreads();

    int wid = t >> 6, lane = t & 63;
    bool isq = lane < 8;
    bool isk = (lane >= 8) && (lane < 16);
    const float* wr  = sWv + lane * 65;
    const float* wr2 = sWqk + (lane & 7) * 65 + (isk ? 8 * 65 : 0);
    float bvl = bv[lane];
    float bql = isq ? bq[lane] : (isk ? bk[lane - 8] : 0.f);

    #pragma unroll 1
    for (int i = 0; i < 8; ++i) {
        int pix = blockIdx.x * 32 + wid * 8 + i;
        float xv = x[(size_t)pix * 64 + lane];
        float accv = bvl, accq = bql;
        #pragma unroll
        for (int cc = 0; cc < 64; ++cc) {
            float xc = __shfl(xv, cc);
            accv = fmaf(xc, wr[cc], accv);
            accq = fmaf(xc, wr2[cc], accq);
        }
        vws[(size_t)pix * 64 + lane] = accv;
        if (out_init) out_init[(size_t)pix * 64 + lane] = xv;
        if (isq)      qws[(size_t)pix * 8 + lane] = accq;
        else if (isk) kws[(size_t)pix * 8 + (lane - 8)] = accq;
    }
}

// ---------------------------------------------------------------------------
// K2 main: per-pixel attention, barrier-free.
// Per-wave LDS W[2968]: Vt[0:1600] (flat1600 V, aliased later as LB),
// Qs[1600:1800(+pad 208)], Kt[1808:2032] ([8][28] transposed K),
// E[2032:2936] ([32][28]+pad, zeroed), R[2936:2968].
// ---------------------------------------------------------------------------
__global__ __launch_bounds__(256) void k2_attn_ws(
    const float* __restrict__ qws, const float* __restrict__ kws,
    const float* __restrict__ vws,
    float* __restrict__ attn, __half* __restrict__ lws)
{
    __shared__ float smem[4 * 2968];

    int tid = threadIdx.x, wid = tid >> 6, lane = tid & 63;
    float* W  = smem + wid * 2968;
    float* Vt = W;            // flat1600: Vt[cv*25+p] = v(cv, patch p)
    float* LB = W;            // [1600] fold-remap buffer (aliases Vt)
    float* Qs = W + 1600;     // [200] flat
    float* Kt = W + 1808;     // [8][28]: Kt[cc*28+m] = Kflat[m*8+cc]
    float* E  = W + 2032;     // [32][28] + 8 pad
    float* R  = W + 2936;     // [32]

    int pix = blockIdx.x * 4 + wid;
    int b = pix >> 14, y = (pix >> 7) & 127, x = pix & 127;
    size_t ibase = (size_t)b << 14;

    // zero E (A-side pad rows/cols stay 0)
    #pragma unroll
    for (int e = lane; e < 904; e += 64) E[e] = 0.f;

    // ---- stage V as flat1600: Vt[lane*25 + p]
    const float* vb = vws + ibase * 64;
    int vbase = lane * 25;
    #pragma unroll
    for (int p = 0; p < 25; ++p) {
        int i5 = div5(p);
        int yy = y + i5 - 2, xx = x + (p - i5 * 5) - 2;
        float val = 0.f;
        if ((unsigned)yy < 128u && (unsigned)xx < 128u)
            val = vb[(size_t)(((yy << 7) + xx) * 64 + lane)];
        Vt[vbase + p] = val;
    }

    // ---- stage Q flat, K transposed
    const float* qb = qws + ibase * 8;
    const float* kb = kws + ibase * 8;
    #pragma unroll
    for (int i = 0; i < 4; ++i) {
        int e = lane + (i << 6);
        if (e < 200) {
            int cq = div25(e), p = e - cq * 25;
            int i5 = div5(p);
            int yy = y + i5 - 2, xx = x + (p - i5 * 5) - 2;
            float qv = 0.f, kv = 0.f;
            if ((unsigned)yy < 128u && (unsigned)xx < 128u) {
                int off = ((yy << 7) + xx) * 8 + cq;
                qv = qb[off];
                kv = kb[off];
            }
            Qs[e] = qv;
            Kt[(e & 7) * 28 + (e >> 3)] = kv;
        }
    }

    // ---- logits[n][m] fp32: Q rows broadcast b128, Kt stride-1 scalar reads
    #pragma unroll
    for (int i = 0; i < 10; ++i) {
        int e = lane + (i << 6);
        if (e < 625) {
            int n = div25(e), m = e - n * 25;
            const float4* qr = (const float4*)(Qs + (n << 3));
            float4 q0 = qr[0], q1 = qr[1];
            const float* kp = Kt + m;
            E[n * 28 + m] = q0.x * kp[0]   + q0.y * kp[28]  + q0.z * kp[56]  + q0.w * kp[84]
                          + q1.x * kp[112] + q1.y * kp[140] + q1.z * kp[168] + q1.w * kp[196];
        }
    }

    // ---- softmax: 2 lanes per row (lanes 0..49)
    if (lane < 50) {
        int n = lane >> 1, hf = lane & 1;
        float* row = E + n * 28;
        int m0 = hf * 12;                 // half0: m 0..12, half1: m 12..24
        float mx = -3.4e38f;
        #pragma unroll
        for (int t = 0; t < 13; ++t) mx = fmaxf(mx, row[m0 + t]);
        mx = fmaxf(mx, __shfl_xor(mx, 1));
        float sum = 0.f;
        #pragma unroll
        for (int t = 0; t < 13; ++t) {
            int m = m0 + t;
            float ev = __expf(row[m] - mx);
            row[m] = ev;                   // m=12 written by both halves, same value
            sum += (hf && t == 0) ? 0.f : ev;
        }
        sum += __shfl_xor(sum, 1);
        R[n] = 1.f / sum;                  // both halves write same value
    }

    // ---- attn output (fp32, exact path)
    float* ab = attn + (size_t)pix * 625;
    #pragma unroll
    for (int i = 0; i < 10; ++i) {
        int e = lane + (i << 6);
        if (e < 625) {
            int n = div25(e), m = e - n * 25;
            ab[e] = E[n * 28 + m] * R[n];
        }
    }

    // ---- PV via MFMA. A = exp rows (f16); B[k][cc] = Vt[k*64+cc] (linear!)
    int h  = lane >> 5;
    int lo = lane & 31;

    half8 afr[2];
    #pragma unroll
    for (int s = 0; s < 2; ++s) {
        const float4* ep = (const float4*)(E + lo * 28 + 16 * s + 8 * h);
        float4 p0 = ep[0], p1 = ep[1];
        afr[s][0] = (_Float16)p0.x; afr[s][1] = (_Float16)p0.y;
        afr[s][2] = (_Float16)p0.z; afr[s][3] = (_Float16)p0.w;
        afr[s][4] = (_Float16)p1.x; afr[s][5] = (_Float16)p1.y;
        afr[s][6] = (_Float16)p1.z; afr[s][7] = (_Float16)p1.w;
    }

    const float* VtL = Vt + lo + (h << 9);   // + h*8*64
    f32x16 acc0 = {0,0,0,0,0,0,0,0,0,0,0,0,0,0,0,0};
    f32x16 acc1 = {0,0,0,0,0,0,0,0,0,0,0,0,0,0,0,0};
    #pragma unroll
    for (int s = 0; s < 2; ++s) {
        half8 b0, b1;
        #pragma unroll
        for (int j = 0; j < 8; ++j) {
            int k = 16 * s + 8 * h + j;       // logical k row
            int off = ((16 * s + j) << 6);    // + h*512 folded into VtL
            float v0 = VtL[off];
            float v1 = VtL[off + 32];
            bool ok = (k < 25);               // rows >=25 are zero
            b0[j] = (_Float16)(ok ? v0 : 0.f);
            b1[j] = (_Float16)(ok ? v1 : 0.f);
        }
        acc0 = __builtin_amdgcn_mfma_f32_32x32x16_f16(afr[s], b0, acc0, 0, 0, 0);
        acc1 = __builtin_amdgcn_mfma_f32_32x32x16_f16(afr[s], b1, acc1, 0, 0, 0);
    }

    // ---- fold-remap: LB[n*64+cc] = local flat (normalized); LB aliases Vt
    #pragma unroll
    for (int r16 = 0; r16 < 16; ++r16) {
        int row = (r16 & 3) + 8 * (r16 >> 2) + 4 * h;
        if (row < 25) {
            float rn = R[row];
            LB[(row << 6) + lo]      = acc0[r16] * rn;
            LB[(row << 6) + 32 + lo] = acc1[r16] * rn;
        }
    }

    // ---- store fp16 local, PLANE layout: lws[(p*NPIX + pix)*64 + c]
    #pragma unroll
    for (int p = 0; p < 25; ++p)
        lws[((size_t)p * NPIX + (size_t)pix) * 64 + lane] = __float2half(LB[lane * 25 + p]);
}

// ---------------------------------------------------------------------------
// K3: vectorized gather fold. 4 pixels per wave; 8B fp16 loads, float4 out.
// out = x + gamma * sum_{i,j} plane[i*5+j] at (y+2-i, x+2-j).
// ---------------------------------------------------------------------------
__global__ __launch_bounds__(256) void k3_fold(
    const float* __restrict__ x, const __half* __restrict__ lws,
    const float* __restrict__ gamma, float* __restrict__ out)
{
    int tid = threadIdx.x, wid = tid >> 6, lane = tid & 63;
    int pix4 = (blockIdx.x * 4 + wid) * 4;
    int b = pix4 >> 14, y = (pix4 >> 7) & 127, x0 = pix4 & 127;
    int sub = lane >> 4;            // pixel 0..3 within group
    int ch4 = (lane & 15) << 2;     // channel group (4 channels)
    size_t ibase = (size_t)b << 14;

    float s0 = 0.f, s1 = 0.f, s2 = 0.f, s3 = 0.f;
    #pragma unroll
    for (int i = 0; i < 5; ++i) {
        int cy = y + 2 - i;
        if ((unsigned)cy >= 128u) continue;        // wave-uniform
        #pragma unroll
        for (int j = 0; j < 5; ++j) {
            int cx = x0 + sub + 2 - j;             // per-lane source pixel
            if ((unsigned)cx < 128u) {
                size_t src = ((size_t)(i * 5 + j) * NPIX + (ibase + (size_t)((cy << 7) + cx))) * 64 + ch4;
                float2 w = *(const float2*)(lws + src);   // 4 fp16
                __half2 h0 = *(__half2*)&w.x, h1 = *(__half2*)&w.y;
                float2 fa = __half22float2(h0), fb = __half22float2(h1);
                s0 += fa.x; s1 += fa.y; s2 += fb.x; s3 += fb.y;
            }
        }
    }

    float g = gamma[0];
    size_t o = ((size_t)pix4 + sub) * 64 + ch4;
    float4 xv = *(const float4*)(x + o);
    float4 r;
    r.x = fmaf(g, s0, xv.x);
    r.y = fmaf(g, s1, xv.y);
    r.z = fmaf(g, s2, xv.z);
    r.w = fmaf(g, s3, xv.w);
    *(float4*)(out + o) = r;
}

// ---------------------------------------------------------------------------
// Fallback path (small ws): R3's proven per-pixel attention + atomic fold.
// ---------------------------------------------------------------------------
__device__ __forceinline__ void attn_core_fb(
    int lane, int y, int x, size_t ibase,
    const float* __restrict__ qws, const float* __restrict__ kws,
    const float* __restrict__ vws, float* __restrict__ attn,
    float* V, float* Qs, float* Ks, float* E, float* R, float vr[25])
{
    const float* vb = vws + ibase * 64;
    #pragma unroll
    for (int p = 0; p < 25; ++p) {
        int i5 = div5(p);
        int yy = y + i5 - 2, xx = x + (p - i5 * 5) - 2;
        float val = 0.f;
        if ((unsigned)yy < 128u && (unsigned)xx < 128u)
            val = vb[(size_t)(((yy << 7) + xx) * 64 + lane)];
        V[p * 65 + lane] = val;
    }
    const float* qb = qws + ibase * 8;
    const float* kb = kws + ibase * 8;
    #pragma unroll
    for (int i = 0; i < 4; ++i) {
        int e = lane + (i << 6);
        if (e < 200) {
            int cq = div25(e), p = e - cq * 25;
            int i5 = div5(p);
            int yy = y + i5 - 2, xx = x + (p - i5 * 5) - 2;
            float qv = 0.f, kv = 0.f;
            if ((unsigned)yy < 128u && (unsigned)xx < 128u) {
                int off = ((yy << 7) + xx) * 8 + cq;
                qv = qb[off];
                kv = kb[off];
            }
            Qs[e] = qv;
            Ks[e] = kv;
        }
    }
    #pragma unroll
    for (int m = 0; m < 25; ++m) {
        int g = (m << 6) + lane;
        int cv = div25(g), p = g - cv * 25;
        vr[m] = V[p * 65 + cv];
    }
    #pragma unroll
    for (int i = 0; i < 10; ++i) {
        int e = lane + (i << 6);
        if (e < 625) {
            int n = div25(e), m = e - n * 25;
            const float4* qr = (const float4*)(Qs + (n << 3));
            const float4* kr = (const float4*)(Ks + (m << 3));
            float4 q0 = qr[0], q1 = qr[1], k0 = kr[0], k1 = kr[1];
            E[n * 28 + m] = q0.x * k0.x + q0.y * k0.y + q0.z * k0.z + q0.w * k0.w
                          + q1.x * k1.x + q1.y * k1.y + q1.z * k1.z + q1.w * k1.w;
        }
    }
    if (lane < 25) {
        float* row = E + lane * 28;
        float mx = -3.4e38f;
        #pragma unroll
        for (int m = 0; m < 25; ++m) mx = fmaxf(mx, row[m]);
        float s = 0.f;
        #pragma unroll
        for (int m = 0; m < 25; ++m) {
            float ev = __expf(row[m] - mx);
            row[m] = ev;
            s += ev;
        }
        R[lane] = 1.f / s;
    }
    float* ab = attn + (ibase + (size_t)((y << 7) + x)) * 625;
    #pragma unroll
    for (int i = 0; i < 10; ++i) {
        int e = lane + (i << 6);
        if (e < 625) {
            int n = div25(e), m = e - n * 25;
            ab[e] = E[n * 28 + m] * R[n];
        }
    }
}

__global__ __launch_bounds__(256) void k2_attn_atomic(
    const float* __restrict__ qws, const float* __restrict__ kws,
    const float* __restrict__ vws, const float* __restrict__ gamma,
    float* __restrict__ out, float* __restrict__ attn)
{
    __shared__ float sV[4][1632];
    __shared__ float sQ[4][200];
    __shared__ float sK[4][200];
    __shared__ float sE[4][704];
    __shared__ float sR[4][32];

    int tid = threadIdx.x, wid = tid >> 6, lane = tid & 63;
    int pix = blockIdx.x * 4 + wid;
    int b = pix >> 14, y = (pix >> 7) & 127, x = pix & 127;
    size_t ibase = (size_t)b << 14;

    float vr[25];
    attn_core_fb(lane, y, x, ibase, qws, kws, vws, attn,
                 sV[wid], sQ[wid], sK[wid], sE[wid], sR[wid], vr);

    float g0 = gamma[0];
    float acc[25];
    float* E = sE[wid];
    float* R = sR[wid];
    #pragma unroll
    for (int n = 0; n < 25; ++n) {
        const float4* er = (const float4*)(E + n * 28);
        float aa = E[n * 28 + 24] * vr[24];
        #pragma unroll
        for (int q4 = 0; q4 < 6; ++q4) {
            float4 ev = er[q4];
            aa = fmaf(ev.x, vr[q4 * 4 + 0], aa);
            aa = fmaf(ev.y, vr[q4 * 4 + 1], aa);
            aa = fmaf(ev.z, vr[q4 * 4 + 2], aa);
            aa = fmaf(ev.w, vr[q4 * 4 + 3], aa);
        }
        acc[n] = aa * (R[n] * g0);
    }

    float* LB = sV[wid];
    #pragma unroll
    for (int n = 0; n < 25; ++n) LB[(n << 6) + lane] = acc[n];

    float* ob = out + ibase * 64;
    #pragma unroll
    for (int p = 0; p < 25; ++p) {
        int i5 = div5(p);
        int ty = y + i5 - 2, tx = x + (p - i5 * 5) - 2;
        if ((unsigned)ty < 128u && (unsigned)tx < 128u)
            atomicAdd(ob + (size_t)(((ty << 7) + tx) * 64 + lane), LB[lane * 25 + p]);
    }
}

// ---------------------------------------------------------------------------
extern "C" void kernel_launch(void* const* d_in, const int* in_sizes, int n_in,
                              void* d_out, int out_size, void* d_ws, size_t ws_size,
                              hipStream_t stream)
{
    const float* x  = (const float*)d_in[0];
    const float* Wq = (const float*)d_in[1];
    const float* bq = (const float*)d_in[2];
    const float* Wk = (const float*)d_in[3];
    const float* bk = (const float*)d_in[4];
    const float* Wv = (const float*)d_in[5];
    const float* bv = (const float*)d_in[6];
    const float* gm = (const float*)d_in[7];

    float* out  = (float*)d_out;               // [4,128,128,64]
    float* attn = out + OUT_ELEMS;             // [4,128,128,25,25]

    float* qws = (float*)d_ws;                 // [NPIX][8]
    float* kws = qws + (size_t)NPIX * 8;       // [NPIX][8]
    float* vws = kws + (size_t)NPIX * 8;       // [NPIX][64]
    __half* lws = (__half*)(vws + (size_t)NPIX * 64);   // [25][NPIX][64] fp16 planes

    const size_t need = (size_t)NPIX * 80 * 4 + (size_t)NPIX * 1600 * 2; // 230.7 MB

    if (ws_size >= need) {
        hipLaunchKernelGGL(k1_qkv, dim3(NPIX / 32), dim3(256), 0, stream,
                           x, Wq, bq, Wk, bk, Wv, bv, qws, kws, vws, (float*)nullptr);
        hipLaunchKernelGGL(k2_attn_ws, dim3(NPIX / 4), dim3(256), 0, stream,
                           qws, kws, vws, attn, lws);
        hipLaunchKernelGGL(k3_fold, dim3(NPIX / 16), dim3(256), 0, stream,
                           x, lws, gm, out);
    } else {
        hipLaunchKernelGGL(k1_qkv, dim3(NPIX / 32), dim3(256), 0, stream,
                           x, Wq, bq, Wk, bk, Wv, bv, qws, kws, vws, out);
        hipLaunchKernelGGL(k2_attn_atomic, dim3(NPIX / 4), dim3(256), 0, stream,
                           qws, kws, vws, gm, out, attn);
    }
}

// Round 8
// 301.776 us; speedup vs baseline: 2.6654x; 1.1064x over previous
//
#include <hip/hip_runtime.h>
#include <hip/hip_fp16.h>

#define NPIX (4*128*128)          // 65536
#define OUT_ELEMS (NPIX*64)       // 4194304

typedef _Float16 half8 __attribute__((ext_vector_type(8)));
typedef float f32x16 __attribute__((ext_vector_type(16)));

__device__ __forceinline__ int div25(int v) { return (v * 5243) >> 17; }   // exact 0..2600
__device__ __forceinline__ int div5(int v)  { return (v * 205) >> 10; }    // exact 0..1000

// ---------------------------------------------------------------------------
// K1: 1x1 convs q/k/v. 2048 blocks; each wave handles 8 pixels.
// ---------------------------------------------------------------------------
__global__ __launch_bounds__(256) void k1_qkv(
    const float* __restrict__ x,
    const float* __restrict__ Wq, const float* __restrict__ bq,
    const float* __restrict__ Wk, const float* __restrict__ bk,
    const float* __restrict__ Wv, const float* __restrict__ bv,
    float* __restrict__ qws, float* __restrict__ kws, float* __restrict__ vws,
    float* __restrict__ out_init)
{
    __shared__ float sWv[64 * 65];
    __shared__ float sWqk[16 * 65];

    int t = threadIdx.x;
    for (int e = t; e < 64 * 64; e += 256) sWv[(e >> 6) * 65 + (e & 63)] = Wv[e];
    for (int e = t; e < 8 * 64; e += 256) {
        int o = e >> 6, c = e & 63;
        sWqk[o * 65 + c]       = Wq[e];
        sWqk[(o + 8) * 65 + c] = Wk[e];
    }
    __syncthreads();

    int wid = t >> 6, lane = t & 63;
    bool isq = lane < 8;
    bool isk = (lane >= 8) && (lane < 16);
    const float* wr  = sWv + lane * 65;
    const float* wr2 = sWqk + (lane & 7) * 65 + (isk ? 8 * 65 : 0);
    float bvl = bv[lane];
    float bql = isq ? bq[lane] : (isk ? bk[lane - 8] : 0.f);

    #pragma unroll 1
    for (int i = 0; i < 8; ++i) {
        int pix = blockIdx.x * 32 + wid * 8 + i;
        float xv = x[(size_t)pix * 64 + lane];
        float accv = bvl, accq = bql;
        #pragma unroll
        for (int cc = 0; cc < 64; ++cc) {
            float xc = __shfl(xv, cc);
            accv = fmaf(xc, wr[cc], accv);
            accq = fmaf(xc, wr2[cc], accq);
        }
        vws[(size_t)pix * 64 + lane] = accv;
        if (out_init) out_init[(size_t)pix * 64 + lane] = xv;
        if (isq)      qws[(size_t)pix * 8 + lane] = accq;
        else if (isk) kws[(size_t)pix * 8 + (lane - 8)] = accq;
    }
}

// ---------------------------------------------------------------------------
// K2 main: per-pixel attention, barrier-free, LDS-diet version.
// Per-wave LDS W[2164 floats]:
//   Qs[0:200]+pad  Kt[204:428] ([8][28] transposed K)  E[428:1332] ([32][28]+8)
//   R[1332:1364]   Vth = (half*)(W+1364): 1600 halves (aliased later as LBh)
// ---------------------------------------------------------------------------
__global__ __launch_bounds__(256) void k2_attn_ws(
    const float* __restrict__ qws, const float* __restrict__ kws,
    const float* __restrict__ vws,
    float* __restrict__ attn, __half* __restrict__ lws)
{
    __shared__ float smem[4 * 2164];

    int tid = threadIdx.x, wid = tid >> 6, lane = tid & 63;
    float* W   = smem + wid * 2164;
    float* Qs  = W;                 // [200]
    float* Kt  = W + 204;           // [8][28]
    float* E   = W + 428;           // [32][28] + 8 pad (zeroed)
    float* R   = W + 1332;          // [32]
    __half* Vth = (__half*)(W + 1364);  // [1600] halves
    __half* LBh = Vth;                   // alias (Vth dead after MFMA)

    int pix = blockIdx.x * 4 + wid;
    int b = pix >> 14, y = (pix >> 7) & 127, x = pix & 127;
    size_t ibase = (size_t)b << 14;

    // ---- zero E with b128 (226 float4s)
    float4 z4 = {0.f, 0.f, 0.f, 0.f};
    #pragma unroll
    for (int i = 0; i < 4; ++i) {
        int idx = lane + (i << 6);
        if (idx < 226) ((float4*)E)[idx] = z4;
    }

    // ---- stage V as fp16 flat1600: Vth[lane*25 + p]
    const float* vb = vws + ibase * 64;
    int vbase = lane * 25;
    #pragma unroll
    for (int p = 0; p < 25; ++p) {
        int i5 = div5(p);
        int yy = y + i5 - 2, xx = x + (p - i5 * 5) - 2;
        float val = 0.f;
        if ((unsigned)yy < 128u && (unsigned)xx < 128u)
            val = vb[(size_t)(((yy << 7) + xx) * 64 + lane)];
        Vth[vbase + p] = __float2half(val);
    }

    // ---- stage Q flat, K transposed (both fp32 — exact logits path)
    const float* qb = qws + ibase * 8;
    const float* kb = kws + ibase * 8;
    #pragma unroll
    for (int i = 0; i < 4; ++i) {
        int e = lane + (i << 6);
        if (e < 200) {
            int cq = div25(e), p = e - cq * 25;
            int i5 = div5(p);
            int yy = y + i5 - 2, xx = x + (p - i5 * 5) - 2;
            float qv = 0.f, kv = 0.f;
            if ((unsigned)yy < 128u && (unsigned)xx < 128u) {
                int off = ((yy << 7) + xx) * 8 + cq;
                qv = qb[off];
                kv = kb[off];
            }
            Qs[e] = qv;
            Kt[(e & 7) * 28 + (e >> 3)] = kv;
        }
    }

    // ---- logits: lane = (m, row-half); K-column in registers.
    // lanes 0..24: m=lane, rows 0..12;  lanes 25..49: m=lane-25, rows 13..24.
    {
        bool act = lane < 50;
        int m_l = (lane < 25) ? lane : lane - 25;
        int n0  = (lane < 25) ? 0 : 13;
        float kreg[8];
        #pragma unroll
        for (int cc = 0; cc < 8; ++cc)
            kreg[cc] = Kt[cc * 28 + m_l];     // lanes>=50 read m_l garbage-safe (in-bounds)
        #pragma unroll
        for (int t = 0; t < 13; ++t) {
            int n = n0 + t;
            bool ok = act && (n < 25);
            int nn = ok ? n : 0;
            const float4* qr = (const float4*)(Qs + (nn << 3));
            float4 q0 = qr[0], q1 = qr[1];
            float s = q0.x * kreg[0] + q0.y * kreg[1] + q0.z * kreg[2] + q0.w * kreg[3]
                    + q1.x * kreg[4] + q1.y * kreg[5] + q1.z * kreg[6] + q1.w * kreg[7];
            if (ok) E[n * 28 + m_l] = s;
        }
    }

    // ---- softmax: 2 lanes per row (lanes 0..49)
    if (lane < 50) {
        int n = lane >> 1, hf = lane & 1;
        float* row = E + n * 28;
        int m0 = hf * 12;                 // half0: m 0..12, half1: m 12..24
        float mx = -3.4e38f;
        #pragma unroll
        for (int t = 0; t < 13; ++t) mx = fmaxf(mx, row[m0 + t]);
        mx = fmaxf(mx, __shfl_xor(mx, 1));
        float sum = 0.f;
        #pragma unroll
        for (int t = 0; t < 13; ++t) {
            int m = m0 + t;
            float ev = __expf(row[m] - mx);
            row[m] = ev;                   // m=12 written by both halves, same value
            sum += (hf && t == 0) ? 0.f : ev;
        }
        sum += __shfl_xor(sum, 1);
        R[n] = 1.f / sum;
    }

    // ---- attn output (fp32, exact path)
    float* ab = attn + (size_t)pix * 625;
    #pragma unroll
    for (int i = 0; i < 10; ++i) {
        int e = lane + (i << 6);
        if (e < 625) {
            int n = div25(e), m = e - n * 25;
            ab[e] = E[n * 28 + m] * R[n];
        }
    }

    // ---- PV via MFMA. A = exp rows (f16); B[k][cc] = Vth[k*64+cc] (linear)
    int h  = lane >> 5;
    int lo = lane & 31;

    half8 afr[2];
    #pragma unroll
    for (int s = 0; s < 2; ++s) {
        const float4* ep = (const float4*)(E + lo * 28 + 16 * s + 8 * h);
        float4 p0 = ep[0], p1 = ep[1];
        afr[s][0] = (_Float16)p0.x; afr[s][1] = (_Float16)p0.y;
        afr[s][2] = (_Float16)p0.z; afr[s][3] = (_Float16)p0.w;
        afr[s][4] = (_Float16)p1.x; afr[s][5] = (_Float16)p1.y;
        afr[s][6] = (_Float16)p1.z; afr[s][7] = (_Float16)p1.w;
    }

    f32x16 acc0 = {0,0,0,0,0,0,0,0,0,0,0,0,0,0,0,0};
    f32x16 acc1 = {0,0,0,0,0,0,0,0,0,0,0,0,0,0,0,0};
    #pragma unroll
    for (int s = 0; s < 2; ++s) {
        half8 b0, b1;
        #pragma unroll
        for (int j = 0; j < 8; ++j) {
            int k = 16 * s + 8 * h + j;            // logical k row
            bool ok = (k < 25);
            int off = ok ? (((16 * s + j) << 6) + (h << 9)) : 0;   // in-bounds clamp
            _Float16 v0 = Vth[off + lo];
            _Float16 v1 = Vth[off + 32 + lo];
            b0[j] = ok ? v0 : (_Float16)0.f;       // B rows k>=25 MUST be 0
            b1[j] = ok ? v1 : (_Float16)0.f;       // (A cols 28..31 are nonzero spill)
        }
        acc0 = __builtin_amdgcn_mfma_f32_32x32x16_f16(afr[s], b0, acc0, 0, 0, 0);
        acc1 = __builtin_amdgcn_mfma_f32_32x32x16_f16(afr[s], b1, acc1, 0, 0, 0);
    }

    // ---- fold-remap in fp16: LBh[n*64+cc] = (half)(acc*R[n]); aliases Vth
    #pragma unroll
    for (int r16 = 0; r16 < 16; ++r16) {
        int row = (r16 & 3) + 8 * (r16 >> 2) + 4 * h;
        if (row < 25) {
            float rn = R[row];
            LBh[(row << 6) + lo]      = __float2half(acc0[r16] * rn);
            LBh[(row << 6) + 32 + lo] = __float2half(acc1[r16] * rn);
        }
    }

    // ---- store fp16 local, PLANE layout: lws[(p*NPIX + pix)*64 + c]
    #pragma unroll
    for (int p = 0; p < 25; ++p)
        lws[((size_t)p * NPIX + (size_t)pix) * 64 + lane] = LBh[lane * 25 + p];
}

// ---------------------------------------------------------------------------
// K3: vectorized gather fold. 4 pixels per wave; 8B fp16 loads, float4 out.
// ---------------------------------------------------------------------------
__global__ __launch_bounds__(256) void k3_fold(
    const float* __restrict__ x, const __half* __restrict__ lws,
    const float* __restrict__ gamma, float* __restrict__ out)
{
    int tid = threadIdx.x, wid = tid >> 6, lane = tid & 63;
    int pix4 = (blockIdx.x * 4 + wid) * 4;
    int b = pix4 >> 14, y = (pix4 >> 7) & 127, x0 = pix4 & 127;
    int sub = lane >> 4;            // pixel 0..3 within group
    int ch4 = (lane & 15) << 2;     // channel group (4 channels)
    size_t ibase = (size_t)b << 14;

    float s0 = 0.f, s1 = 0.f, s2 = 0.f, s3 = 0.f;
    #pragma unroll
    for (int i = 0; i < 5; ++i) {
        int cy = y + 2 - i;
        if ((unsigned)cy >= 128u) continue;        // wave-uniform
        #pragma unroll
        for (int j = 0; j < 5; ++j) {
            int cx = x0 + sub + 2 - j;             // per-lane source pixel
            if ((unsigned)cx < 128u) {
                size_t src = ((size_t)(i * 5 + j) * NPIX + (ibase + (size_t)((cy << 7) + cx))) * 64 + ch4;
                float2 w = *(const float2*)(lws + src);   // 4 fp16
                __half2 h0 = *(__half2*)&w.x, h1 = *(__half2*)&w.y;
                float2 fa = __half22float2(h0), fb = __half22float2(h1);
                s0 += fa.x; s1 += fa.y; s2 += fb.x; s3 += fb.y;
            }
        }
    }

    float g = gamma[0];
    size_t o = ((size_t)pix4 + sub) * 64 + ch4;
    float4 xv = *(const float4*)(x + o);
    float4 r;
    r.x = fmaf(g, s0, xv.x);
    r.y = fmaf(g, s1, xv.y);
    r.z = fmaf(g, s2, xv.z);
    r.w = fmaf(g, s3, xv.w);
    *(float4*)(out + o) = r;
}

// ---------------------------------------------------------------------------
// Fallback path (small ws): R3's proven per-pixel attention + atomic fold.
// ---------------------------------------------------------------------------
__device__ __forceinline__ void attn_core_fb(
    int lane, int y, int x, size_t ibase,
    const float* __restrict__ qws, const float* __restrict__ kws,
    const float* __restrict__ vws, float* __restrict__ attn,
    float* V, float* Qs, float* Ks, float* E, float* R, float vr[25])
{
    const float* vb = vws + ibase * 64;
    #pragma unroll
    for (int p = 0; p < 25; ++p) {
        int i5 = div5(p);
        int yy = y + i5 - 2, xx = x + (p - i5 * 5) - 2;
        float val = 0.f;
        if ((unsigned)yy < 128u && (unsigned)xx < 128u)
            val = vb[(size_t)(((yy << 7) + xx) * 64 + lane)];
        V[p * 65 + lane] = val;
    }
    const float* qb = qws + ibase * 8;
    const float* kb = kws + ibase * 8;
    #pragma unroll
    for (int i = 0; i < 4; ++i) {
        int e = lane + (i << 6);
        if (e < 200) {
            int cq = div25(e), p = e - cq * 25;
            int i5 = div5(p);
            int yy = y + i5 - 2, xx = x + (p - i5 * 5) - 2;
            float qv = 0.f, kv = 0.f;
            if ((unsigned)yy < 128u && (unsigned)xx < 128u) {
                int off = ((yy << 7) + xx) * 8 + cq;
                qv = qb[off];
                kv = kb[off];
            }
            Qs[e] = qv;
            Ks[e] = kv;
        }
    }
    #pragma unroll
    for (int m = 0; m < 25; ++m) {
        int g = (m << 6) + lane;
        int cv = div25(g), p = g - cv * 25;
        vr[m] = V[p * 65 + cv];
    }
    #pragma unroll
    for (int i = 0; i < 10; ++i) {
        int e = lane + (i << 6);
        if (e < 625) {
            int n = div25(e), m = e - n * 25;
            const float4* qr = (const float4*)(Qs + (n << 3));
            const float4* kr = (const float4*)(Ks + (m << 3));
            float4 q0 = qr[0], q1 = qr[1], k0 = kr[0], k1 = kr[1];
            E[n * 28 + m] = q0.x * k0.x + q0.y * k0.y + q0.z * k0.z + q0.w * k0.w
                          + q1.x * k1.x + q1.y * k1.y + q1.z * k1.z + q1.w * k1.w;
        }
    }
    if (lane < 25) {
        float* row = E + lane * 28;
        float mx = -3.4e38f;
        #pragma unroll
        for (int m = 0; m < 25; ++m) mx = fmaxf(mx, row[m]);
        float s = 0.f;
        #pragma unroll
        for (int m = 0; m < 25; ++m) {
            float ev = __expf(row[m] - mx);
            row[m] = ev;
            s += ev;
        }
        R[lane] = 1.f / s;
    }
    float* ab = attn + (ibase + (size_t)((y << 7) + x)) * 625;
    #pragma unroll
    for (int i = 0; i < 10; ++i) {
        int e = lane + (i << 6);
        if (e < 625) {
            int n = div25(e), m = e - n * 25;
            ab[e] = E[n * 28 + m] * R[n];
        }
    }
}

__global__ __launch_bounds__(256) void k2_attn_atomic(
    const float* __restrict__ qws, const float* __restrict__ kws,
    const float* __restrict__ vws, const float* __restrict__ gamma,
    float* __restrict__ out, float* __restrict__ attn)
{
    __shared__ float sV[4][1632];
    __shared__ float sQ[4][200];
    __shared__ float sK[4][200];
    __shared__ float sE[4][704];
    __shared__ float sR[4][32];

    int tid = threadIdx.x, wid = tid >> 6, lane = tid & 63;
    int pix = blockIdx.x * 4 + wid;
    int b = pix >> 14, y = (pix >> 7) & 127, x = pix & 127;
    size_t ibase = (size_t)b << 14;

    float vr[25];
    attn_core_fb(lane, y, x, ibase, qws, kws, vws, attn,
                 sV[wid], sQ[wid], sK[wid], sE[wid], sR[wid], vr);

    float g0 = gamma[0];
    float acc[25];
    float* E = sE[wid];
    float* R = sR[wid];
    #pragma unroll
    for (int n = 0; n < 25; ++n) {
        const float4* er = (const float4*)(E + n * 28);
        float aa = E[n * 28 + 24] * vr[24];
        #pragma unroll
        for (int q4 = 0; q4 < 6; ++q4) {
            float4 ev = er[q4];
            aa = fmaf(ev.x, vr[q4 * 4 + 0], aa);
            aa = fmaf(ev.y, vr[q4 * 4 + 1], aa);
            aa = fmaf(ev.z, vr[q4 * 4 + 2], aa);
            aa = fmaf(ev.w, vr[q4 * 4 + 3], aa);
        }
        acc[n] = aa * (R[n] * g0);
    }

    float* LB = sV[wid];
    #pragma unroll
    for (int n = 0; n < 25; ++n) LB[(n << 6) + lane] = acc[n];

    float* ob = out + ibase * 64;
    #pragma unroll
    for (int p = 0; p < 25; ++p) {
        int i5 = div5(p);
        int ty = y + i5 - 2, tx = x + (p - i5 * 5) - 2;
        if ((unsigned)ty < 128u && (unsigned)tx < 128u)
            atomicAdd(ob + (size_t)(((ty << 7) + tx) * 64 + lane), LB[lane * 25 + p]);
    }
}

// ---------------------------------------------------------------------------
extern "C" void kernel_launch(void* const* d_in, const int* in_sizes, int n_in,
                              void* d_out, int out_size, void* d_ws, size_t ws_size,
                              hipStream_t stream)
{
    const float* x  = (const float*)d_in[0];
    const float* Wq = (const float*)d_in[1];
    const float* bq = (const float*)d_in[2];
    const float* Wk = (const float*)d_in[3];
    const float* bk = (const float*)d_in[4];
    const float* Wv = (const float*)d_in[5];
    const float* bv = (const float*)d_in[6];
    const float* gm = (const float*)d_in[7];

    float* out  = (float*)d_out;               // [4,128,128,64]
    float* attn = out + OUT_ELEMS;             // [4,128,128,25,25]

    float* qws = (float*)d_ws;                 // [NPIX][8]
    float* kws = qws + (size_t)NPIX * 8;       // [NPIX][8]
    float* vws = kws + (size_t)NPIX * 8;       // [NPIX][64]
    __half* lws = (__half*)(vws + (size_t)NPIX * 64);   // [25][NPIX][64] fp16 planes

    const size_t need = (size_t)NPIX * 80 * 4 + (size_t)NPIX * 1600 * 2; // 230.7 MB

    if (ws_size >= need) {
        hipLaunchKernelGGL(k1_qkv, dim3(NPIX / 32), dim3(256), 0, stream,
                           x, Wq, bq, Wk, bk, Wv, bv, qws, kws, vws, (float*)nullptr);
        hipLaunchKernelGGL(k2_attn_ws, dim3(NPIX / 4), dim3(256), 0, stream,
                           qws, kws, vws, attn, lws);
        hipLaunchKernelGGL(k3_fold, dim3(NPIX / 16), dim3(256), 0, stream,
                           x, lws, gm, out);
    } else {
        hipLaunchKernelGGL(k1_qkv, dim3(NPIX / 32), dim3(256), 0, stream,
                           x, Wq, bq, Wk, bk, Wv, bv, qws, kws, vws, out);
        hipLaunchKernelGGL(k2_attn_atomic, dim3(NPIX / 4), dim3(256), 0, stream,
                           qws, kws, vws, gm, out, attn);
    }
}

// Round 9
// 279.110 us; speedup vs baseline: 2.8819x; 1.0812x over previous
//
#include <hip/hip_runtime.h>
#include <hip/hip_fp16.h>

#define NPIX (4*128*128)          // 65536
#define OUT_ELEMS (NPIX*64)       // 4194304

typedef _Float16 half8 __attribute__((ext_vector_type(8)));
typedef float f32x16 __attribute__((ext_vector_type(16)));

__device__ __forceinline__ int div25(int v) { return (v * 5243) >> 17; }   // exact 0..2600
__device__ __forceinline__ int div5(int v)  { return (v * 205) >> 10; }    // exact 0..1000

// ---------------------------------------------------------------------------
// K1: 1x1 convs q/k/v. 2048 blocks; each wave handles 8 pixels.
// ---------------------------------------------------------------------------
__global__ __launch_bounds__(256) void k1_qkv(
    const float* __restrict__ x,
    const float* __restrict__ Wq, const float* __restrict__ bq,
    const float* __restrict__ Wk, const float* __restrict__ bk,
    const float* __restrict__ Wv, const float* __restrict__ bv,
    float* __restrict__ qws, float* __restrict__ kws, float* __restrict__ vws,
    float* __restrict__ out_init)
{
    __shared__ float sWv[64 * 65];
    __shared__ float sWqk[16 * 65];

    int t = threadIdx.x;
    for (int e = t; e < 64 * 64; e += 256) sWv[(e >> 6) * 65 + (e & 63)] = Wv[e];
    for (int e = t; e < 8 * 64; e += 256) {
        int o = e >> 6, c = e & 63;
        sWqk[o * 65 + c]       = Wq[e];
        sWqk[(o + 8) * 65 + c] = Wk[e];
    }
    __syncthreads();

    int wid = t >> 6, lane = t & 63;
    bool isq = lane < 8;
    bool isk = (lane >= 8) && (lane < 16);
    const float* wr  = sWv + lane * 65;
    const float* wr2 = sWqk + (lane & 7) * 65 + (isk ? 8 * 65 : 0);
    float bvl = bv[lane];
    float bql = isq ? bq[lane] : (isk ? bk[lane - 8] : 0.f);

    #pragma unroll 1
    for (int i = 0; i < 8; ++i) {
        int pix = blockIdx.x * 32 + wid * 8 + i;
        float xv = x[(size_t)pix * 64 + lane];
        float accv = bvl, accq = bql;
        #pragma unroll
        for (int cc = 0; cc < 64; ++cc) {
            float xc = __shfl(xv, cc);
            accv = fmaf(xc, wr[cc], accv);
            accq = fmaf(xc, wr2[cc], accq);
        }
        vws[(size_t)pix * 64 + lane] = accv;
        if (out_init) out_init[(size_t)pix * 64 + lane] = xv;
        if (isq)      qws[(size_t)pix * 8 + lane] = accq;
        else if (isk) kws[(size_t)pix * 8 + (lane - 8)] = accq;
    }
}

// ---------------------------------------------------------------------------
// K2 main: per-pixel attention, barrier-free, 5-blocks/CU version.
// Per-wave LDS W[1984 floats]:
//   Qs[0:200]  Kt[200:424] ([8][28])  E[424:1152] ([26][28], row 25 zeroed)
//   R[1152:1184]  Vth = (half*)(W+1184): 1600 halves (aliased later as LBh)
// MFMA garbage-safety: A-frag rows m>=25 read garbage (R/Vth bits) -> D rows
// >=25 garbage -> never stored (row independence of D). Only the k-dim needs
// finite zeros: E cols 25..27 of rows 0..24, and E row 25 (spill read of the
// lo=24 fragment). B rows k>=25 are reg-masked to 0.
// ---------------------------------------------------------------------------
__global__ __launch_bounds__(256) void k2_attn_ws(
    const float* __restrict__ qws, const float* __restrict__ kws,
    const float* __restrict__ vws,
    float* __restrict__ attn, __half* __restrict__ lws)
{
    __shared__ float smem[4 * 1984];

    int tid = threadIdx.x, wid = tid >> 6, lane = tid & 63;
    float* W   = smem + wid * 1984;
    float* Qs  = W;                 // [200]
    float* Kt  = W + 200;           // [8][28]
    float* E   = W + 424;           // [26][28]
    float* R   = W + 1152;          // [32]
    __half* Vth = (__half*)(W + 1184);  // [1600] halves
    __half* LBh = Vth;                   // alias (Vth dead after MFMA)

    int pix = blockIdx.x * 4 + wid;
    int b = pix >> 14, y = (pix >> 7) & 127, x = pix & 127;
    size_t ibase = (size_t)b << 14;

    // ---- zero the k-dim pad: cols 25..27 of rows 0..24, and all of row 25
    if (lane < 25) {
        float* er = E + lane * 28;
        er[25] = 0.f; er[26] = 0.f; er[27] = 0.f;
    }
    if (lane < 28) E[700 + lane] = 0.f;

    // ---- stage V as fp16 flat1600: Vth[lane*25 + p]
    const float* vb = vws + ibase * 64;
    int vbase = lane * 25;
    #pragma unroll
    for (int p = 0; p < 25; ++p) {
        int i5 = div5(p);
        int yy = y + i5 - 2, xx = x + (p - i5 * 5) - 2;
        float val = 0.f;
        if ((unsigned)yy < 128u && (unsigned)xx < 128u)
            val = vb[(size_t)(((yy << 7) + xx) * 64 + lane)];
        Vth[vbase + p] = __float2half(val);
    }

    // ---- stage Q flat, K transposed (both fp32 — exact logits path)
    const float* qb = qws + ibase * 8;
    const float* kb = kws + ibase * 8;
    #pragma unroll
    for (int i = 0; i < 4; ++i) {
        int e = lane + (i << 6);
        if (e < 200) {
            int cq = div25(e), p = e - cq * 25;
            int i5 = div5(p);
            int yy = y + i5 - 2, xx = x + (p - i5 * 5) - 2;
            float qv = 0.f, kv = 0.f;
            if ((unsigned)yy < 128u && (unsigned)xx < 128u) {
                int off = ((yy << 7) + xx) * 8 + cq;
                qv = qb[off];
                kv = kb[off];
            }
            Qs[e] = qv;
            Kt[(e & 7) * 28 + (e >> 3)] = kv;
        }
    }

    // ---- logits: lane = (m, row-half); K-column in registers.
    {
        bool act = lane < 50;
        int m_l = (lane < 25) ? lane : lane - 25;
        int n0  = (lane < 25) ? 0 : 13;
        float kreg[8];
        #pragma unroll
        for (int cc = 0; cc < 8; ++cc)
            kreg[cc] = Kt[cc * 28 + m_l];
        #pragma unroll
        for (int t = 0; t < 13; ++t) {
            int n = n0 + t;
            bool ok = act && (n < 25);
            int nn = ok ? n : 0;
            const float4* qr = (const float4*)(Qs + (nn << 3));
            float4 q0 = qr[0], q1 = qr[1];
            float s = q0.x * kreg[0] + q0.y * kreg[1] + q0.z * kreg[2] + q0.w * kreg[3]
                    + q1.x * kreg[4] + q1.y * kreg[5] + q1.z * kreg[6] + q1.w * kreg[7];
            if (ok) E[n * 28 + m_l] = s;
        }
    }

    // ---- softmax: 2 lanes per row (lanes 0..49)
    if (lane < 50) {
        int n = lane >> 1, hf = lane & 1;
        float* row = E + n * 28;
        int m0 = hf * 12;
        float mx = -3.4e38f;
        #pragma unroll
        for (int t = 0; t < 13; ++t) mx = fmaxf(mx, row[m0 + t]);
        mx = fmaxf(mx, __shfl_xor(mx, 1));
        float sum = 0.f;
        #pragma unroll
        for (int t = 0; t < 13; ++t) {
            int m = m0 + t;
            float ev = __expf(row[m] - mx);
            row[m] = ev;
            sum += (hf && t == 0) ? 0.f : ev;
        }
        sum += __shfl_xor(sum, 1);
        R[n] = 1.f / sum;
    }

    // ---- attn output (fp32, exact path)
    float* ab = attn + (size_t)pix * 625;
    #pragma unroll
    for (int i = 0; i < 10; ++i) {
        int e = lane + (i << 6);
        if (e < 625) {
            int n = div25(e), m = e - n * 25;
            ab[e] = E[n * 28 + m] * R[n];
        }
    }

    // ---- PV via MFMA. A = exp rows (f16); B[k][cc] = Vth[k*64+cc] (linear)
    int h  = lane >> 5;
    int lo = lane & 31;

    half8 afr[2];
    #pragma unroll
    for (int s = 0; s < 2; ++s) {
        const float4* ep = (const float4*)(E + lo * 28 + 16 * s + 8 * h);
        float4 p0 = ep[0], p1 = ep[1];
        afr[s][0] = (_Float16)p0.x; afr[s][1] = (_Float16)p0.y;
        afr[s][2] = (_Float16)p0.z; afr[s][3] = (_Float16)p0.w;
        afr[s][4] = (_Float16)p1.x; afr[s][5] = (_Float16)p1.y;
        afr[s][6] = (_Float16)p1.z; afr[s][7] = (_Float16)p1.w;
    }

    f32x16 acc0 = {0,0,0,0,0,0,0,0,0,0,0,0,0,0,0,0};
    f32x16 acc1 = {0,0,0,0,0,0,0,0,0,0,0,0,0,0,0,0};
    #pragma unroll
    for (int s = 0; s < 2; ++s) {
        half8 b0, b1;
        #pragma unroll
        for (int j = 0; j < 8; ++j) {
            int k = 16 * s + 8 * h + j;            // logical k row
            bool ok = (k < 25);
            int off = ok ? (((16 * s + j) << 6) + (h << 9)) : 0;   // in-bounds clamp
            _Float16 v0 = Vth[off + lo];
            _Float16 v1 = Vth[off + 32 + lo];
            b0[j] = ok ? v0 : (_Float16)0.f;       // B rows k>=25 MUST be 0
            b1[j] = ok ? v1 : (_Float16)0.f;
        }
        acc0 = __builtin_amdgcn_mfma_f32_32x32x16_f16(afr[s], b0, acc0, 0, 0, 0);
        acc1 = __builtin_amdgcn_mfma_f32_32x32x16_f16(afr[s], b1, acc1, 0, 0, 0);
    }

    // ---- fold-remap in fp16: LBh[n*64+cc] = (half)(acc*R[n]); aliases Vth
    #pragma unroll
    for (int r16 = 0; r16 < 16; ++r16) {
        int row = (r16 & 3) + 8 * (r16 >> 2) + 4 * h;
        if (row < 25) {
            float rn = R[row];
            LBh[(row << 6) + lo]      = __float2half(acc0[r16] * rn);
            LBh[(row << 6) + 32 + lo] = __float2half(acc1[r16] * rn);
        }
    }

    // ---- store fp16 local, PLANE layout: lws[(p*NPIX + pix)*64 + c]
    #pragma unroll
    for (int p = 0; p < 25; ++p)
        lws[((size_t)p * NPIX + (size_t)pix) * 64 + lane] = LBh[lane * 25 + p];
}

// ---------------------------------------------------------------------------
// K3: vectorized gather fold. 4 pixels per wave; 8B fp16 loads, float4 out.
// ---------------------------------------------------------------------------
__global__ __launch_bounds__(256) void k3_fold(
    const float* __restrict__ x, const __half* __restrict__ lws,
    const float* __restrict__ gamma, float* __restrict__ out)
{
    int tid = threadIdx.x, wid = tid >> 6, lane = tid & 63;
    int pix4 = (blockIdx.x * 4 + wid) * 4;
    int b = pix4 >> 14, y = (pix4 >> 7) & 127, x0 = pix4 & 127;
    int sub = lane >> 4;            // pixel 0..3 within group
    int ch4 = (lane & 15) << 2;     // channel group (4 channels)
    size_t ibase = (size_t)b << 14;

    float s0 = 0.f, s1 = 0.f, s2 = 0.f, s3 = 0.f;
    #pragma unroll
    for (int i = 0; i < 5; ++i) {
        int cy = y + 2 - i;
        if ((unsigned)cy >= 128u) continue;        // wave-uniform
        #pragma unroll
        for (int j = 0; j < 5; ++j) {
            int cx = x0 + sub + 2 - j;             // per-lane source pixel
            if ((unsigned)cx < 128u) {
                size_t src = ((size_t)(i * 5 + j) * NPIX + (ibase + (size_t)((cy << 7) + cx))) * 64 + ch4;
                float2 w = *(const float2*)(lws + src);   // 4 fp16
                __half2 h0 = *(__half2*)&w.x, h1 = *(__half2*)&w.y;
                float2 fa = __half22float2(h0), fb = __half22float2(h1);
                s0 += fa.x; s1 += fa.y; s2 += fb.x; s3 += fb.y;
            }
        }
    }

    float g = gamma[0];
    size_t o = ((size_t)pix4 + sub) * 64 + ch4;
    float4 xv = *(const float4*)(x + o);
    float4 r;
    r.x = fmaf(g, s0, xv.x);
    r.y = fmaf(g, s1, xv.y);
    r.z = fmaf(g, s2, xv.z);
    r.w = fmaf(g, s3, xv.w);
    *(float4*)(out + o) = r;
}

// ---------------------------------------------------------------------------
// Fallback path (small ws): R3's proven per-pixel attention + atomic fold.
// ---------------------------------------------------------------------------
__device__ __forceinline__ void attn_core_fb(
    int lane, int y, int x, size_t ibase,
    const float* __restrict__ qws, const float* __restrict__ kws,
    const float* __restrict__ vws, float* __restrict__ attn,
    float* V, float* Qs, float* Ks, float* E, float* R, float vr[25])
{
    const float* vb = vws + ibase * 64;
    #pragma unroll
    for (int p = 0; p < 25; ++p) {
        int i5 = div5(p);
        int yy = y + i5 - 2, xx = x + (p - i5 * 5) - 2;
        float val = 0.f;
        if ((unsigned)yy < 128u && (unsigned)xx < 128u)
            val = vb[(size_t)(((yy << 7) + xx) * 64 + lane)];
        V[p * 65 + lane] = val;
    }
    const float* qb = qws + ibase * 8;
    const float* kb = kws + ibase * 8;
    #pragma unroll
    for (int i = 0; i < 4; ++i) {
        int e = lane + (i << 6);
        if (e < 200) {
            int cq = div25(e), p = e - cq * 25;
            int i5 = div5(p);
            int yy = y + i5 - 2, xx = x + (p - i5 * 5) - 2;
            float qv = 0.f, kv = 0.f;
            if ((unsigned)yy < 128u && (unsigned)xx < 128u) {
                int off = ((yy << 7) + xx) * 8 + cq;
                qv = qb[off];
                kv = kb[off];
            }
            Qs[e] = qv;
            Ks[e] = kv;
        }
    }
    #pragma unroll
    for (int m = 0; m < 25; ++m) {
        int g = (m << 6) + lane;
        int cv = div25(g), p = g - cv * 25;
        vr[m] = V[p * 65 + cv];
    }
    #pragma unroll
    for (int i = 0; i < 10; ++i) {
        int e = lane + (i << 6);
        if (e < 625) {
            int n = div25(e), m = e - n * 25;
            const float4* qr = (const float4*)(Qs + (n << 3));
            const float4* kr = (const float4*)(Ks + (m << 3));
            float4 q0 = qr[0], q1 = qr[1], k0 = kr[0], k1 = kr[1];
            E[n * 28 + m] = q0.x * k0.x + q0.y * k0.y + q0.z * k0.z + q0.w * k0.w
                          + q1.x * k1.x + q1.y * k1.y + q1.z * k1.z + q1.w * k1.w;
        }
    }
    if (lane < 25) {
        float* row = E + lane * 28;
        float mx = -3.4e38f;
        #pragma unroll
        for (int m = 0; m < 25; ++m) mx = fmaxf(mx, row[m]);
        float s = 0.f;
        #pragma unroll
        for (int m = 0; m < 25; ++m) {
            float ev = __expf(row[m] - mx);
            row[m] = ev;
            s += ev;
        }
        R[lane] = 1.f / s;
    }
    float* ab = attn + (ibase + (size_t)((y << 7) + x)) * 625;
    #pragma unroll
    for (int i = 0; i < 10; ++i) {
        int e = lane + (i << 6);
        if (e < 625) {
            int n = div25(e), m = e - n * 25;
            ab[e] = E[n * 28 + m] * R[n];
        }
    }
}

__global__ __launch_bounds__(256) void k2_attn_atomic(
    const float* __restrict__ qws, const float* __restrict__ kws,
    const float* __restrict__ vws, const float* __restrict__ gamma,
    float* __restrict__ out, float* __restrict__ attn)
{
    __shared__ float sV[4][1632];
    __shared__ float sQ[4][200];
    __shared__ float sK[4][200];
    __shared__ float sE[4][704];
    __shared__ float sR[4][32];

    int tid = threadIdx.x, wid = tid >> 6, lane = tid & 63;
    int pix = blockIdx.x * 4 + wid;
    int b = pix >> 14, y = (pix >> 7) & 127, x = pix & 127;
    size_t ibase = (size_t)b << 14;

    float vr[25];
    attn_core_fb(lane, y, x, ibase, qws, kws, vws, attn,
                 sV[wid], sQ[wid], sK[wid], sE[wid], sR[wid], vr);

    float g0 = gamma[0];
    float acc[25];
    float* E = sE[wid];
    float* R = sR[wid];
    #pragma unroll
    for (int n = 0; n < 25; ++n) {
        const float4* er = (const float4*)(E + n * 28);
        float aa = E[n * 28 + 24] * vr[24];
        #pragma unroll
        for (int q4 = 0; q4 < 6; ++q4) {
            float4 ev = er[q4];
            aa = fmaf(ev.x, vr[q4 * 4 + 0], aa);
            aa = fmaf(ev.y, vr[q4 * 4 + 1], aa);
            aa = fmaf(ev.z, vr[q4 * 4 + 2], aa);
            aa = fmaf(ev.w, vr[q4 * 4 + 3], aa);
        }
        acc[n] = aa * (R[n] * g0);
    }

    float* LB = sV[wid];
    #pragma unroll
    for (int n = 0; n < 25; ++n) LB[(n << 6) + lane] = acc[n];

    float* ob = out + ibase * 64;
    #pragma unroll
    for (int p = 0; p < 25; ++p) {
        int i5 = div5(p);
        int ty = y + i5 - 2, tx = x + (p - i5 * 5) - 2;
        if ((unsigned)ty < 128u && (unsigned)tx < 128u)
            atomicAdd(ob + (size_t)(((ty << 7) + tx) * 64 + lane), LB[lane * 25 + p]);
    }
}

// ---------------------------------------------------------------------------
extern "C" void kernel_launch(void* const* d_in, const int* in_sizes, int n_in,
                              void* d_out, int out_size, void* d_ws, size_t ws_size,
                              hipStream_t stream)
{
    const float* x  = (const float*)d_in[0];
    const float* Wq = (const float*)d_in[1];
    const float* bq = (const float*)d_in[2];
    const float* Wk = (const float*)d_in[3];
    const float* bk = (const float*)d_in[4];
    const float* Wv = (const float*)d_in[5];
    const float* bv = (const float*)d_in[6];
    const float* gm = (const float*)d_in[7];

    float* out  = (float*)d_out;               // [4,128,128,64]
    float* attn = out + OUT_ELEMS;             // [4,128,128,25,25]

    float* qws = (float*)d_ws;                 // [NPIX][8]
    float* kws = qws + (size_t)NPIX * 8;       // [NPIX][8]
    float* vws = kws + (size_t)NPIX * 8;       // [NPIX][64]
    __half* lws = (__half*)(vws + (size_t)NPIX * 64);   // [25][NPIX][64] fp16 planes

    const size_t need = (size_t)NPIX * 80 * 4 + (size_t)NPIX * 1600 * 2; // 230.7 MB

    if (ws_size >= need) {
        hipLaunchKernelGGL(k1_qkv, dim3(NPIX / 32), dim3(256), 0, stream,
                           x, Wq, bq, Wk, bk, Wv, bv, qws, kws, vws, (float*)nullptr);
        hipLaunchKernelGGL(k2_attn_ws, dim3(NPIX / 4), dim3(256), 0, stream,
                           qws, kws, vws, attn, lws);
        hipLaunchKernelGGL(k3_fold, dim3(NPIX / 16), dim3(256), 0, stream,
                           x, lws, gm, out);
    } else {
        hipLaunchKernelGGL(k1_qkv, dim3(NPIX / 32), dim3(256), 0, stream,
                           x, Wq, bq, Wk, bk, Wv, bv, qws, kws, vws, out);
        hipLaunchKernelGGL(k2_attn_atomic, dim3(NPIX / 4), dim3(256), 0, stream,
                           qws, kws, vws, gm, out, attn);
    }
}